// Round 4
// baseline (1195.310 us; speedup 1.0000x reference)
//
#include <hip/hip_runtime.h>

// XSimGCL / LightGCN propagation on MI355X.
// w = D^{-1/2} x  =>  each layer is an unweighted neighbor MEAN; no edge values.
// CSR build = two-phase binned counting sort:
//   phase0: hist over (bucket = row>>7, group = blockIdx&7)  [9376 counters]
//   scan  : one small block; bucket-major order => doubles as CSR bucket bases
//   phase1: append packed (col<<7 | row&127) into (b,g) region; random-write
//           working set = 9376 tail lines (~37KB, L2-resident)
//   phase2: per-bucket LDS counting sort -> row_ptr slice + col_idx slice
//           (random writes confined to ~20KB L2-resident CSR slice)

#define EMBED_DIM 64
#define NUM_LAYERS 3
#define RSHIFT 7            // 128 rows per bucket
#define RMASK 127

// ---------------- phase 0: (bucket,group) histogram ----------------

__global__ void bhist_kernel(const int* __restrict__ rows, int* __restrict__ cnt8, int E) {
    int e = blockIdx.x * 256 + threadIdx.x;
    if (e >= E) return;
    int r = rows[e];
    atomicAdd(&cnt8[((r >> RSHIFT) << 3) | (blockIdx.x & 7)], 1);
}

// ---------------- single-block scan over M counters ----------------
// writes exclusive scan to ptr8 AND cur8; sentinels ptr8[M]=E, row_ptr[N]=E.

__global__ void scan_small_kernel(const int* __restrict__ cnt8, int M,
                                  int* __restrict__ ptr8, int* __restrict__ cur8,
                                  int* __restrict__ row_ptr, int N, int E) {
    __shared__ int sc[256];
    int tid = threadIdx.x;
    int carry = 0;
    for (int base = 0; base < M; base += 256) {
        int i = base + tid;
        int v = (i < M) ? cnt8[i] : 0;
        sc[tid] = v;
        __syncthreads();
        for (int off = 1; off < 256; off <<= 1) {
            int t = (tid >= off) ? sc[tid - off] : 0;
            __syncthreads();
            sc[tid] += t;
            __syncthreads();
        }
        int ex = carry + sc[tid] - v;
        if (i < M) { ptr8[i] = ex; cur8[i] = ex; }
        carry += sc[255];
        __syncthreads();
    }
    if (tid == 0) { ptr8[M] = E; row_ptr[N] = E; }
}

// ---------------- phase 1: bin edges (packed) ----------------

__global__ void bin_kernel(const int* __restrict__ rows, const int* __restrict__ cols,
                           int* __restrict__ cur8, int* __restrict__ bin, int E) {
    int e = blockIdx.x * 256 + threadIdx.x;
    if (e >= E) return;
    int r = rows[e];
    int p = atomicAdd(&cur8[((r >> RSHIFT) << 3) | (blockIdx.x & 7)], 1);
    bin[p] = (cols[e] << RSHIFT) | (r & RMASK);
}

// ---------------- phase 2: per-bucket LDS counting sort ----------------

__global__ __launch_bounds__(256) void csr_kernel(const int* __restrict__ bin,
                                                  const int* __restrict__ ptr8,
                                                  int* __restrict__ row_ptr,
                                                  int* __restrict__ col_idx, int N) {
    __shared__ int h[128], sc[128], cur[128];
    int b   = blockIdx.x;
    int tid = threadIdx.x;
    int s = ptr8[b << 3];
    int e = ptr8[(b << 3) + 8];
    if (tid < 128) h[tid] = 0;
    __syncthreads();
    for (int j = s + tid; j < e; j += 256) atomicAdd(&h[bin[j] & RMASK], 1);
    __syncthreads();
    if (tid < 128) sc[tid] = h[tid];
    __syncthreads();
    for (int off = 1; off < 128; off <<= 1) {
        int t = 0;
        if (tid < 128 && tid >= off) t = sc[tid - off];
        __syncthreads();
        if (tid < 128) sc[tid] += t;
        __syncthreads();
    }
    if (tid < 128) {
        int ex = sc[tid] - h[tid];
        cur[tid] = ex;
        int gr = (b << RSHIFT) + tid;
        if (gr < N) row_ptr[gr] = s + ex;
    }
    __syncthreads();
    for (int j = s + tid; j < e; j += 256) {
        int v = bin[j];
        int p = s + atomicAdd(&cur[v & RMASK], 1);
        col_idx[p] = v >> RSHIFT;
    }
}

// ---------------- w0 = D^{-1/2} * concat(user_emb, item_emb) ----------------

__global__ void w0_kernel(const float* __restrict__ user_emb, const float* __restrict__ item_emb,
                          const int* __restrict__ row_ptr, float* __restrict__ w0, int U, int N) {
    int n    = (blockIdx.x * blockDim.x + threadIdx.x) >> 6;
    int lane = threadIdx.x & 63;
    if (n >= N) return;
    int d = row_ptr[n + 1] - row_ptr[n];
    float rs = (d > 0) ? rsqrtf((float)d) : 0.0f;
    float v  = (n < U) ? user_emb[(size_t)n * EMBED_DIM + lane]
                       : item_emb[(size_t)(n - U) * EMBED_DIM + lane];
    w0[(size_t)n * EMBED_DIM + lane] = v * rs;
}

// ---------------- SpMM: neighbor mean (one wave per row) ----------------

__global__ __launch_bounds__(256) void spmm_kernel(const int* __restrict__ row_ptr,
                                                   const int* __restrict__ col_idx,
                                                   const float* __restrict__ x,
                                                   float* __restrict__ y, int N) {
    int w    = (blockIdx.x * blockDim.x + threadIdx.x) >> 6;
    int lane = threadIdx.x & 63;
    if (w >= N) return;
    int s = row_ptr[w];
    int e = row_ptr[w + 1];
    float acc = 0.0f;
    int j = s;
    for (; j + 3 < e; j += 4) {
        int c0 = col_idx[j],     c1 = col_idx[j + 1];
        int c2 = col_idx[j + 2], c3 = col_idx[j + 3];
        float x0 = x[(size_t)c0 * EMBED_DIM + lane];
        float x1 = x[(size_t)c1 * EMBED_DIM + lane];
        float x2 = x[(size_t)c2 * EMBED_DIM + lane];
        float x3 = x[(size_t)c3 * EMBED_DIM + lane];
        acc += x0; acc += x1; acc += x2; acc += x3;
    }
    for (; j < e; ++j) acc += x[(size_t)col_idx[j] * EMBED_DIM + lane];
    float inv = (e > s) ? (1.0f / (float)(e - s)) : 0.0f;
    y[(size_t)w * EMBED_DIM + lane] = acc * inv;
}

// ---------------- readout ----------------

__global__ void add_sel_kernel(const float* __restrict__ y, const int* __restrict__ user_ids,
                               const int* __restrict__ item_ids, float* __restrict__ acc_sel,
                               int B, int U) {
    int w    = (blockIdx.x * blockDim.x + threadIdx.x) >> 6;
    int lane = threadIdx.x & 63;
    if (w >= 2 * B) return;
    int row = (w < B) ? user_ids[w] : (item_ids[w - B] + U);
    acc_sel[(size_t)w * EMBED_DIM + lane] += y[(size_t)row * EMBED_DIM + lane];
}

// out[b] = sqrt(du)*sqrt(di) * dot(accU[b], accI[b]) / 9
__global__ void dot_kernel(const float* __restrict__ acc_sel, const int* __restrict__ row_ptr,
                           const int* __restrict__ user_ids, const int* __restrict__ item_ids,
                           float* __restrict__ out, int B, int U) {
    int w    = (blockIdx.x * blockDim.x + threadIdx.x) >> 6;
    int lane = threadIdx.x & 63;
    if (w >= B) return;
    float p = acc_sel[(size_t)w * EMBED_DIM + lane] * acc_sel[(size_t)(B + w) * EMBED_DIM + lane];
#pragma unroll
    for (int off = 32; off > 0; off >>= 1) p += __shfl_down(p, off, 64);
    if (lane == 0) {
        int ur = user_ids[w];
        int ir = item_ids[w] + U;
        float du = (float)(row_ptr[ur + 1] - row_ptr[ur]);
        float di = (float)(row_ptr[ir + 1] - row_ptr[ir]);
        out[w] = p * sqrtf(du) * sqrtf(di) * (1.0f / (NUM_LAYERS * NUM_LAYERS));
    }
}

// ---------------- launch ----------------

extern "C" void kernel_launch(void* const* d_in, const int* in_sizes, int n_in,
                              void* d_out, int out_size, void* d_ws, size_t ws_size,
                              hipStream_t stream) {
    const float* user_emb = (const float*)d_in[0];
    const float* item_emb = (const float*)d_in[1];
    // d_in[2] (vals) unused: reconstructed algebraically from degrees
    const int*   rows     = (const int*)d_in[3];
    const int*   cols     = (const int*)d_in[4];
    const int*   user_ids = (const int*)d_in[5];
    const int*   item_ids = (const int*)d_in[6];
    float*       out      = (float*)d_out;

    const int U = in_sizes[0] / EMBED_DIM;
    const int I = in_sizes[1] / EMBED_DIM;
    const int E = in_sizes[2];
    const int B = in_sizes[5];
    const int N = U + I;
    const int NB = (N + RMASK) >> RSHIFT;   // buckets of 128 rows
    const int M  = NB << 3;                 // (bucket,group) counters

    // workspace layout
    char* w = (char*)d_ws;
    float* x       = (float*)w; w += (size_t)N * EMBED_DIM * sizeof(float);
    float* y       = (float*)w; w += (size_t)N * EMBED_DIM * sizeof(float);
    int*   bin     = (int*)w;   w += (size_t)E * sizeof(int);
    int*   col_idx = (int*)w;   w += (size_t)E * sizeof(int);
    int*   row_ptr = (int*)w;   w += (size_t)(N + 1) * sizeof(int);
    int*   cnt8    = (int*)w;   w += (size_t)M * sizeof(int);
    int*   ptr8    = (int*)w;   w += (size_t)(M + 1) * sizeof(int);
    int*   cur8    = (int*)w;   w += (size_t)M * sizeof(int);
    float* acc_sel = (float*)w; w += (size_t)2 * B * EMBED_DIM * sizeof(float);

    const int T = 256;
    const int GE = (E + T - 1) / T;  // identical grid for bhist & bin (same g mapping)

    hipMemsetAsync(cnt8, 0, (size_t)M * sizeof(int), stream);
    hipMemsetAsync(acc_sel, 0, (size_t)2 * B * EMBED_DIM * sizeof(float), stream);

    // CSR build: binned counting sort
    bhist_kernel<<<GE, T, 0, stream>>>(rows, cnt8, E);
    scan_small_kernel<<<1, T, 0, stream>>>(cnt8, M, ptr8, cur8, row_ptr, N, E);
    bin_kernel<<<GE, T, 0, stream>>>(rows, cols, cur8, bin, E);
    csr_kernel<<<NB, T, 0, stream>>>(bin, ptr8, row_ptr, col_idx, N);

    // w0 = D^{-1/2} * concat(embeddings)
    w0_kernel<<<(N * 64 + T - 1) / T, T, 0, stream>>>(user_emb, item_emb, row_ptr, x, U, N);

    // 3 propagation layers (neighbor mean), ping-pong x<->y
    float* cur = x;
    float* nxt = y;
    for (int layer = 0; layer < NUM_LAYERS; ++layer) {
        spmm_kernel<<<(N * 64 + T - 1) / T, T, 0, stream>>>(row_ptr, col_idx, cur, nxt, N);
        add_sel_kernel<<<(2 * B * 64 + T - 1) / T, T, 0, stream>>>(nxt, user_ids, item_ids,
                                                                   acc_sel, B, U);
        float* tmp = cur; cur = nxt; nxt = tmp;
    }

    dot_kernel<<<(B * 64 + T - 1) / T, T, 0, stream>>>(acc_sel, row_ptr, user_ids, item_ids,
                                                       out, B, U);
}

// Round 5
// 705.811 us; speedup vs baseline: 1.6935x; 1.6935x over previous
//
#include <hip/hip_runtime.h>

// XSimGCL / LightGCN propagation on MI355X.
// w = D^{-1/2} x  =>  each layer is an unweighted neighbor MEAN; no edge values.
//
// CSR build = LDS-staged counting sort. Lesson from r2/r4 rocprof: scattered
// 4B global stores pay ~64B HBM writeback each (L2 does not merge partial
// lines across wave instructions: 146-367MB writes for 16MB payload). So every
// global write here is a contiguous run staged through LDS:
//   bhist: LDS hist per tile -> one global atomic per (block,bucket)
//   scan : bucket bases (== CSR bucket bases)
//   split: tile -> LDS reorder (bucket-grouped) -> contiguous run copies
//   csr  : per-bucket LDS counting sort -> row_ptr slice + full-line col_idx

#define EMBED_DIM 64
#define NUM_LAYERS 3
#define RSHIFT 8            // 256 rows per bucket
#define RMASK 255
#define NBMAX 640           // supports N <= 163840
#define TE 12288            // edges per tile (fits LDS staging)
#define OUT_CAP 15360       // csr out-staging capacity (avg bucket ~10.2K)

// ---------------- bhist: bucket histogram, LDS-aggregated ----------------

__global__ __launch_bounds__(256) void bhist_kernel(const int* __restrict__ rows,
                                                    int* __restrict__ cnt, int E, int NB) {
    __shared__ int h[NBMAX];
    int tid = threadIdx.x;
    for (int i = tid; i < NB; i += 256) h[i] = 0;
    __syncthreads();
    int e0 = blockIdx.x * TE, e1 = min(e0 + TE, E);
    for (int j = e0 + tid; j < e1; j += 256) atomicAdd(&h[rows[j] >> RSHIFT], 1);
    __syncthreads();
    for (int b = tid; b < NB; b += 256)
        if (h[b]) atomicAdd(&cnt[b], h[b]);
}

// ---------------- scan: bucket bases (single block) ----------------

__global__ void scan_kernel(const int* __restrict__ cnt, int NB, int* __restrict__ ptr,
                            int* __restrict__ gcur, int* __restrict__ row_ptr, int N, int E) {
    __shared__ int sc[256];
    int tid = threadIdx.x;
    int carry = 0;
    for (int base = 0; base < NB; base += 256) {
        int i = base + tid;
        int v = (i < NB) ? cnt[i] : 0;
        sc[tid] = v;
        __syncthreads();
        for (int off = 1; off < 256; off <<= 1) {
            int t = (tid >= off) ? sc[tid - off] : 0;
            __syncthreads();
            sc[tid] += t;
            __syncthreads();
        }
        int ex = carry + sc[tid] - v;
        if (i < NB) { ptr[i] = ex; gcur[i] = ex; }
        carry += sc[255];
        __syncthreads();
    }
    if (tid == 0) { ptr[NB] = E; row_ptr[N] = E; }
}

// ---------------- split: tile -> LDS bucket-grouped -> run copies ----------------

__global__ __launch_bounds__(256) void split_kernel(const int* __restrict__ rows,
                                                    const int* __restrict__ cols,
                                                    int* __restrict__ gcur,
                                                    int* __restrict__ bin, int E, int NB) {
    __shared__ int h[NBMAX], exl[NBMAX], curb[NBMAX], gb[NBMAX];
    __shared__ int sc[256];
    __shared__ int stage[TE];
    int tid = threadIdx.x;
    for (int i = tid; i < NB; i += 256) h[i] = 0;
    __syncthreads();
    int e0 = blockIdx.x * TE, e1 = min(e0 + TE, E);
    // phase a: tile histogram
    for (int j = e0 + tid; j < e1; j += 256) atomicAdd(&h[rows[j] >> RSHIFT], 1);
    __syncthreads();
    // phase b: exclusive scan of h over NB (tile-local), + global reservation
    int carry = 0;
    for (int base = 0; base < NB; base += 256) {
        int i = base + tid;
        int v = (i < NB) ? h[i] : 0;
        sc[tid] = v;
        __syncthreads();
        for (int off = 1; off < 256; off <<= 1) {
            int t = (tid >= off) ? sc[tid - off] : 0;
            __syncthreads();
            sc[tid] += t;
            __syncthreads();
        }
        if (i < NB) exl[i] = carry + sc[tid] - v;
        carry += sc[255];
        __syncthreads();
    }
    for (int b = tid; b < NB; b += 256) {
        curb[b] = exl[b];
        gb[b]   = h[b] ? atomicAdd(&gcur[b], h[b]) : 0;
    }
    __syncthreads();
    // phase c: place packed entries into LDS, bucket-grouped
    for (int j = e0 + tid; j < e1; j += 256) {
        int r = rows[j];
        int b = r >> RSHIFT;
        int pos = atomicAdd(&curb[b], 1);
        stage[pos] = (cols[j] << RSHIFT) | (r & RMASK);
    }
    __syncthreads();
    // phase d: one wave per bucket, copy runs out contiguously
    int wid = tid >> 6, lane = tid & 63;
    for (int b = wid; b < NB; b += 4) {
        int cnt_b = h[b];
        int st = exl[b], g = gb[b];
        for (int k = lane; k < cnt_b; k += 64) bin[g + k] = stage[st + k];
    }
}

// ---------------- csr: per-bucket LDS counting sort ----------------

__global__ __launch_bounds__(256) void csr_kernel(const int* __restrict__ bin,
                                                  const int* __restrict__ ptr,
                                                  int* __restrict__ row_ptr,
                                                  int* __restrict__ col_idx, int N) {
    __shared__ int h2[256], cur2[256];
    __shared__ int outst[OUT_CAP];
    int b   = blockIdx.x;
    int tid = threadIdx.x;
    int s = ptr[b], e = ptr[b + 1];
    int cnt = e - s;
    h2[tid] = 0;
    __syncthreads();
    for (int j = s + tid; j < e; j += 256) atomicAdd(&h2[bin[j] & RMASK], 1);
    __syncthreads();
    // exclusive scan (Hillis-Steele on copy)
    cur2[tid] = h2[tid];
    __syncthreads();
    for (int off = 1; off < 256; off <<= 1) {
        int t = (tid >= off) ? cur2[tid - off] : 0;
        __syncthreads();
        cur2[tid] += t;
        __syncthreads();
    }
    cur2[tid] -= h2[tid];  // exclusive
    int gr = (b << RSHIFT) + tid;
    if (gr < N) row_ptr[gr] = s + cur2[tid];
    __syncthreads();
    if (cnt <= OUT_CAP) {
        for (int j = s + tid; j < e; j += 256) {
            int v = bin[j];
            int p = atomicAdd(&cur2[v & RMASK], 1);
            outst[p] = v >> RSHIFT;
        }
        __syncthreads();
        for (int j = tid; j < cnt; j += 256) col_idx[s + j] = outst[j];
    } else {  // safety fallback (never hit at these sizes)
        for (int j = s + tid; j < e; j += 256) {
            int v = bin[j];
            int p = atomicAdd(&cur2[v & RMASK], 1);
            col_idx[s + p] = v >> RSHIFT;
        }
    }
}

// ---------------- w0 = D^{-1/2} * concat(user_emb, item_emb) ----------------

__global__ void w0_kernel(const float* __restrict__ user_emb, const float* __restrict__ item_emb,
                          const int* __restrict__ row_ptr, float* __restrict__ w0, int U, int N) {
    int n    = (blockIdx.x * blockDim.x + threadIdx.x) >> 6;
    int lane = threadIdx.x & 63;
    if (n >= N) return;
    int d = row_ptr[n + 1] - row_ptr[n];
    float rs = (d > 0) ? rsqrtf((float)d) : 0.0f;
    float v  = (n < U) ? user_emb[(size_t)n * EMBED_DIM + lane]
                       : item_emb[(size_t)(n - U) * EMBED_DIM + lane];
    w0[(size_t)n * EMBED_DIM + lane] = v * rs;
}

// ---------------- SpMM: neighbor mean (one wave per row) ----------------

__global__ __launch_bounds__(256) void spmm_kernel(const int* __restrict__ row_ptr,
                                                   const int* __restrict__ col_idx,
                                                   const float* __restrict__ x,
                                                   float* __restrict__ y, int N) {
    int w    = (blockIdx.x * blockDim.x + threadIdx.x) >> 6;
    int lane = threadIdx.x & 63;
    if (w >= N) return;
    int s = row_ptr[w];
    int e = row_ptr[w + 1];
    float acc = 0.0f;
    int j = s;
    for (; j + 3 < e; j += 4) {
        int c0 = col_idx[j],     c1 = col_idx[j + 1];
        int c2 = col_idx[j + 2], c3 = col_idx[j + 3];
        float x0 = x[(size_t)c0 * EMBED_DIM + lane];
        float x1 = x[(size_t)c1 * EMBED_DIM + lane];
        float x2 = x[(size_t)c2 * EMBED_DIM + lane];
        float x3 = x[(size_t)c3 * EMBED_DIM + lane];
        acc += x0; acc += x1; acc += x2; acc += x3;
    }
    for (; j < e; ++j) acc += x[(size_t)col_idx[j] * EMBED_DIM + lane];
    float inv = (e > s) ? (1.0f / (float)(e - s)) : 0.0f;
    y[(size_t)w * EMBED_DIM + lane] = acc * inv;
}

// ---------------- readout ----------------

__global__ void add_sel_kernel(const float* __restrict__ y, const int* __restrict__ user_ids,
                               const int* __restrict__ item_ids, float* __restrict__ acc_sel,
                               int B, int U) {
    int w    = (blockIdx.x * blockDim.x + threadIdx.x) >> 6;
    int lane = threadIdx.x & 63;
    if (w >= 2 * B) return;
    int row = (w < B) ? user_ids[w] : (item_ids[w - B] + U);
    acc_sel[(size_t)w * EMBED_DIM + lane] += y[(size_t)row * EMBED_DIM + lane];
}

// out[b] = sqrt(du)*sqrt(di) * dot(accU[b], accI[b]) / 9
__global__ void dot_kernel(const float* __restrict__ acc_sel, const int* __restrict__ row_ptr,
                           const int* __restrict__ user_ids, const int* __restrict__ item_ids,
                           float* __restrict__ out, int B, int U) {
    int w    = (blockIdx.x * blockDim.x + threadIdx.x) >> 6;
    int lane = threadIdx.x & 63;
    if (w >= B) return;
    float p = acc_sel[(size_t)w * EMBED_DIM + lane] * acc_sel[(size_t)(B + w) * EMBED_DIM + lane];
#pragma unroll
    for (int off = 32; off > 0; off >>= 1) p += __shfl_down(p, off, 64);
    if (lane == 0) {
        int ur = user_ids[w];
        int ir = item_ids[w] + U;
        float du = (float)(row_ptr[ur + 1] - row_ptr[ur]);
        float di = (float)(row_ptr[ir + 1] - row_ptr[ir]);
        out[w] = p * sqrtf(du) * sqrtf(di) * (1.0f / (NUM_LAYERS * NUM_LAYERS));
    }
}

// ---------------- launch ----------------

extern "C" void kernel_launch(void* const* d_in, const int* in_sizes, int n_in,
                              void* d_out, int out_size, void* d_ws, size_t ws_size,
                              hipStream_t stream) {
    const float* user_emb = (const float*)d_in[0];
    const float* item_emb = (const float*)d_in[1];
    // d_in[2] (vals) unused: reconstructed algebraically from degrees
    const int*   rows     = (const int*)d_in[3];
    const int*   cols     = (const int*)d_in[4];
    const int*   user_ids = (const int*)d_in[5];
    const int*   item_ids = (const int*)d_in[6];
    float*       out      = (float*)d_out;

    const int U = in_sizes[0] / EMBED_DIM;
    const int I = in_sizes[1] / EMBED_DIM;
    const int E = in_sizes[2];
    const int B = in_sizes[5];
    const int N = U + I;
    const int NB = (N + RMASK) >> RSHIFT;   // 256-row buckets

    // workspace layout
    char* w = (char*)d_ws;
    float* x       = (float*)w; w += (size_t)N * EMBED_DIM * sizeof(float);
    float* y       = (float*)w; w += (size_t)N * EMBED_DIM * sizeof(float);
    int*   bin     = (int*)w;   w += (size_t)E * sizeof(int);
    int*   col_idx = (int*)w;   w += (size_t)E * sizeof(int);
    int*   row_ptr = (int*)w;   w += (size_t)(N + 1) * sizeof(int);
    int*   cnt     = (int*)w;   w += (size_t)NB * sizeof(int);
    int*   ptr     = (int*)w;   w += (size_t)(NB + 1) * sizeof(int);
    int*   gcur    = (int*)w;   w += (size_t)NB * sizeof(int);
    float* acc_sel = (float*)w; w += (size_t)2 * B * EMBED_DIM * sizeof(float);

    const int T = 256;
    const int GE = (E + TE - 1) / TE;

    hipMemsetAsync(cnt, 0, (size_t)NB * sizeof(int), stream);
    hipMemsetAsync(acc_sel, 0, (size_t)2 * B * EMBED_DIM * sizeof(float), stream);

    // CSR build: LDS-staged counting sort
    bhist_kernel<<<GE, T, 0, stream>>>(rows, cnt, E, NB);
    scan_kernel<<<1, T, 0, stream>>>(cnt, NB, ptr, gcur, row_ptr, N, E);
    split_kernel<<<GE, T, 0, stream>>>(rows, cols, gcur, bin, E, NB);
    csr_kernel<<<NB, T, 0, stream>>>(bin, ptr, row_ptr, col_idx, N);

    // w0 = D^{-1/2} * concat(embeddings)
    w0_kernel<<<(N * 64 + T - 1) / T, T, 0, stream>>>(user_emb, item_emb, row_ptr, x, U, N);

    // 3 propagation layers (neighbor mean), ping-pong x<->y
    float* cur = x;
    float* nxt = y;
    for (int layer = 0; layer < NUM_LAYERS; ++layer) {
        spmm_kernel<<<(N * 64 + T - 1) / T, T, 0, stream>>>(row_ptr, col_idx, cur, nxt, N);
        add_sel_kernel<<<(2 * B * 64 + T - 1) / T, T, 0, stream>>>(nxt, user_ids, item_ids,
                                                                   acc_sel, B, U);
        float* tmp = cur; cur = nxt; nxt = tmp;
    }

    dot_kernel<<<(B * 64 + T - 1) / T, T, 0, stream>>>(acc_sel, row_ptr, user_ids, item_ids,
                                                       out, B, U);
}

// Round 6
// 534.262 us; speedup vs baseline: 2.2373x; 1.3211x over previous
//
#include <hip/hip_runtime.h>

// XSimGCL / LightGCN propagation on MI355X.
// w = D^{-1/2} x  =>  each layer is an unweighted neighbor MEAN; no edge values.
// r5 lesson: spmm is gather-BW bound (FETCH 404MB vs 54MB ideal). This round:
// propagation state stored as packed bf16 pairs (uint = 2 dims) -> 128B rows,
// halved gather traffic + halved L2 working set. fp32 accumulation in-register.
// CSR build stays LDS-staged (r4 lesson: scattered 4B global stores pay ~64B
// HBM writeback each; every global write must be a contiguous run).

#define EMBED_DIM 64
#define NUM_LAYERS 3
#define RSHIFT 8            // 256 rows per bucket
#define RMASK 255
#define NBMAX 640           // supports N <= 163840
#define TE 12288            // edges per tile (fits LDS staging)
#define OUT_CAP 15360       // csr out-staging capacity (avg bucket ~10.2K)

// ---------------- bf16 pair helpers ----------------

__device__ __forceinline__ unsigned bf16pair(float a, float b) {
    unsigned ia = __float_as_uint(a);
    unsigned ib = __float_as_uint(b);
    ia = (ia + 0x7fffu + ((ia >> 16) & 1u)) >> 16;          // RNE, low half
    ib = (ib + 0x7fffu + ((ib >> 16) & 1u)) & 0xffff0000u;  // RNE, high half
    return ia | ib;
}
__device__ __forceinline__ float bf_lo(unsigned u) { return __uint_as_float(u << 16); }
__device__ __forceinline__ float bf_hi(unsigned u) { return __uint_as_float(u & 0xffff0000u); }

// ---------------- bhist: bucket histogram, LDS-aggregated ----------------

__global__ __launch_bounds__(256) void bhist_kernel(const int* __restrict__ rows,
                                                    int* __restrict__ cnt, int E, int NB) {
    __shared__ int h[NBMAX];
    int tid = threadIdx.x;
    for (int i = tid; i < NB; i += 256) h[i] = 0;
    __syncthreads();
    int e0 = blockIdx.x * TE, e1 = min(e0 + TE, E);
    for (int j = e0 + tid; j < e1; j += 256) atomicAdd(&h[rows[j] >> RSHIFT], 1);
    __syncthreads();
    for (int b = tid; b < NB; b += 256)
        if (h[b]) atomicAdd(&cnt[b], h[b]);
}

// ---------------- scan: bucket bases (single block) ----------------

__global__ void scan_kernel(const int* __restrict__ cnt, int NB, int* __restrict__ ptr,
                            int* __restrict__ gcur, int* __restrict__ row_ptr, int N, int E) {
    __shared__ int sc[256];
    int tid = threadIdx.x;
    int carry = 0;
    for (int base = 0; base < NB; base += 256) {
        int i = base + tid;
        int v = (i < NB) ? cnt[i] : 0;
        sc[tid] = v;
        __syncthreads();
        for (int off = 1; off < 256; off <<= 1) {
            int t = (tid >= off) ? sc[tid - off] : 0;
            __syncthreads();
            sc[tid] += t;
            __syncthreads();
        }
        int ex = carry + sc[tid] - v;
        if (i < NB) { ptr[i] = ex; gcur[i] = ex; }
        carry += sc[255];
        __syncthreads();
    }
    if (tid == 0) { ptr[NB] = E; row_ptr[N] = E; }
}

// ---------------- split: tile -> LDS bucket-grouped -> run copies ----------------

__global__ __launch_bounds__(256) void split_kernel(const int* __restrict__ rows,
                                                    const int* __restrict__ cols,
                                                    int* __restrict__ gcur,
                                                    int* __restrict__ bin, int E, int NB) {
    __shared__ int h[NBMAX], exl[NBMAX], curb[NBMAX], gb[NBMAX];
    __shared__ int sc[256];
    __shared__ int stage[TE];
    int tid = threadIdx.x;
    for (int i = tid; i < NB; i += 256) h[i] = 0;
    __syncthreads();
    int e0 = blockIdx.x * TE, e1 = min(e0 + TE, E);
    for (int j = e0 + tid; j < e1; j += 256) atomicAdd(&h[rows[j] >> RSHIFT], 1);
    __syncthreads();
    int carry = 0;
    for (int base = 0; base < NB; base += 256) {
        int i = base + tid;
        int v = (i < NB) ? h[i] : 0;
        sc[tid] = v;
        __syncthreads();
        for (int off = 1; off < 256; off <<= 1) {
            int t = (tid >= off) ? sc[tid - off] : 0;
            __syncthreads();
            sc[tid] += t;
            __syncthreads();
        }
        if (i < NB) exl[i] = carry + sc[tid] - v;
        carry += sc[255];
        __syncthreads();
    }
    for (int b = tid; b < NB; b += 256) {
        curb[b] = exl[b];
        gb[b]   = h[b] ? atomicAdd(&gcur[b], h[b]) : 0;
    }
    __syncthreads();
    for (int j = e0 + tid; j < e1; j += 256) {
        int r = rows[j];
        int b = r >> RSHIFT;
        int pos = atomicAdd(&curb[b], 1);
        stage[pos] = (cols[j] << RSHIFT) | (r & RMASK);
    }
    __syncthreads();
    int wid = tid >> 6, lane = tid & 63;
    for (int b = wid; b < NB; b += 4) {
        int cnt_b = h[b];
        int st = exl[b], g = gb[b];
        for (int k = lane; k < cnt_b; k += 64) bin[g + k] = stage[st + k];
    }
}

// ---------------- csr: per-bucket LDS counting sort ----------------

__global__ __launch_bounds__(256) void csr_kernel(const int* __restrict__ bin,
                                                  const int* __restrict__ ptr,
                                                  int* __restrict__ row_ptr,
                                                  int* __restrict__ col_idx, int N) {
    __shared__ int h2[256], cur2[256];
    __shared__ int outst[OUT_CAP];
    int b   = blockIdx.x;
    int tid = threadIdx.x;
    int s = ptr[b], e = ptr[b + 1];
    int cnt = e - s;
    h2[tid] = 0;
    __syncthreads();
    for (int j = s + tid; j < e; j += 256) atomicAdd(&h2[bin[j] & RMASK], 1);
    __syncthreads();
    cur2[tid] = h2[tid];
    __syncthreads();
    for (int off = 1; off < 256; off <<= 1) {
        int t = (tid >= off) ? cur2[tid - off] : 0;
        __syncthreads();
        cur2[tid] += t;
        __syncthreads();
    }
    cur2[tid] -= h2[tid];  // exclusive
    int gr = (b << RSHIFT) + tid;
    if (gr < N) row_ptr[gr] = s + cur2[tid];
    __syncthreads();
    if (cnt <= OUT_CAP) {
        for (int j = s + tid; j < e; j += 256) {
            int v = bin[j];
            int p = atomicAdd(&cur2[v & RMASK], 1);
            outst[p] = v >> RSHIFT;
        }
        __syncthreads();
        for (int j = tid; j < cnt; j += 256) col_idx[s + j] = outst[j];
    } else {  // safety fallback (never hit at these sizes)
        for (int j = s + tid; j < e; j += 256) {
            int v = bin[j];
            int p = atomicAdd(&cur2[v & RMASK], 1);
            col_idx[s + p] = v >> RSHIFT;
        }
    }
}

// ---------------- w0 = bf16pack(D^{-1/2} * concat(user_emb, item_emb)) ----------------

__global__ void w0_kernel(const float2* __restrict__ ue, const float2* __restrict__ ie,
                          const int* __restrict__ row_ptr, unsigned* __restrict__ w0,
                          int U, int N) {
    int t = blockIdx.x * blockDim.x + threadIdx.x;
    if (t >= N * 32) return;
    int n = t >> 5;
    int d = row_ptr[n + 1] - row_ptr[n];
    float rs = (d > 0) ? rsqrtf((float)d) : 0.0f;
    float2 v = (n < U) ? ue[t] : ie[t - U * 32];
    w0[t] = bf16pair(v.x * rs, v.y * rs);
}

// ---------------- SpMM: neighbor mean, bf16 rows (one wave per row) ----------------
// lanes 0-31 process edges [s, mid), lanes 32-63 [mid, e); each half gathers
// 128B bf16 rows; fp32 accumulate; cross-half shfl_xor combine; half 0 stores.

__global__ __launch_bounds__(256) void spmm_kernel(const int* __restrict__ row_ptr,
                                                   const int* __restrict__ col_idx,
                                                   const unsigned* __restrict__ x2,
                                                   unsigned* __restrict__ y2, int N) {
    int w    = (blockIdx.x * blockDim.x + threadIdx.x) >> 6;
    int lane = threadIdx.x & 63;
    if (w >= N) return;
    int s = row_ptr[w];
    int e = row_ptr[w + 1];
    int cnt = e - s;
    int half = lane >> 5, sub = lane & 31;
    int mid = s + ((cnt + 1) >> 1);
    int j  = half ? mid : s;
    int j1 = half ? e : mid;
    float aL = 0.0f, aH = 0.0f;
    for (; j + 3 < j1; j += 4) {
        int c0 = col_idx[j],     c1 = col_idx[j + 1];
        int c2 = col_idx[j + 2], c3 = col_idx[j + 3];
        unsigned u0 = x2[(size_t)c0 * 32 + sub];
        unsigned u1 = x2[(size_t)c1 * 32 + sub];
        unsigned u2 = x2[(size_t)c2 * 32 + sub];
        unsigned u3 = x2[(size_t)c3 * 32 + sub];
        aL += bf_lo(u0); aH += bf_hi(u0);
        aL += bf_lo(u1); aH += bf_hi(u1);
        aL += bf_lo(u2); aH += bf_hi(u2);
        aL += bf_lo(u3); aH += bf_hi(u3);
    }
    for (; j < j1; ++j) {
        unsigned u = x2[(size_t)col_idx[j] * 32 + sub];
        aL += bf_lo(u); aH += bf_hi(u);
    }
    aL += __shfl_xor(aL, 32, 64);
    aH += __shfl_xor(aH, 32, 64);
    if (half == 0) {
        float inv = (cnt > 0) ? (1.0f / (float)cnt) : 0.0f;
        y2[(size_t)w * 32 + sub] = bf16pair(aL * inv, aH * inv);
    }
}

// ---------------- readout ----------------

__global__ void add_sel_kernel(const unsigned* __restrict__ y2, const int* __restrict__ user_ids,
                               const int* __restrict__ item_ids, float2* __restrict__ acc_sel,
                               int B, int U) {
    int t = blockIdx.x * blockDim.x + threadIdx.x;
    if (t >= 2 * B * 32) return;
    int w = t >> 5, sub = t & 31;
    int row = (w < B) ? user_ids[w] : (item_ids[w - B] + U);
    unsigned u = y2[(size_t)row * 32 + sub];
    float2 a = acc_sel[t];
    a.x += bf_lo(u);
    a.y += bf_hi(u);
    acc_sel[t] = a;
}

// out[b] = sqrt(du)*sqrt(di) * dot(accU[b], accI[b]) / 9
__global__ void dot_kernel(const float* __restrict__ acc_sel, const int* __restrict__ row_ptr,
                           const int* __restrict__ user_ids, const int* __restrict__ item_ids,
                           float* __restrict__ out, int B, int U) {
    int w    = (blockIdx.x * blockDim.x + threadIdx.x) >> 6;
    int lane = threadIdx.x & 63;
    if (w >= B) return;
    float p = acc_sel[(size_t)w * EMBED_DIM + lane] * acc_sel[(size_t)(B + w) * EMBED_DIM + lane];
#pragma unroll
    for (int off = 32; off > 0; off >>= 1) p += __shfl_down(p, off, 64);
    if (lane == 0) {
        int ur = user_ids[w];
        int ir = item_ids[w] + U;
        float du = (float)(row_ptr[ur + 1] - row_ptr[ur]);
        float di = (float)(row_ptr[ir + 1] - row_ptr[ir]);
        out[w] = p * sqrtf(du) * sqrtf(di) * (1.0f / (NUM_LAYERS * NUM_LAYERS));
    }
}

// ---------------- launch ----------------

extern "C" void kernel_launch(void* const* d_in, const int* in_sizes, int n_in,
                              void* d_out, int out_size, void* d_ws, size_t ws_size,
                              hipStream_t stream) {
    const float* user_emb = (const float*)d_in[0];
    const float* item_emb = (const float*)d_in[1];
    // d_in[2] (vals) unused: reconstructed algebraically from degrees
    const int*   rows     = (const int*)d_in[3];
    const int*   cols     = (const int*)d_in[4];
    const int*   user_ids = (const int*)d_in[5];
    const int*   item_ids = (const int*)d_in[6];
    float*       out      = (float*)d_out;

    const int U = in_sizes[0] / EMBED_DIM;
    const int I = in_sizes[1] / EMBED_DIM;
    const int E = in_sizes[2];
    const int B = in_sizes[5];
    const int N = U + I;
    const int NB = (N + RMASK) >> RSHIFT;   // 256-row buckets

    // workspace layout
    char* w = (char*)d_ws;
    unsigned* x2      = (unsigned*)w; w += (size_t)N * 32 * sizeof(unsigned);
    unsigned* y2      = (unsigned*)w; w += (size_t)N * 32 * sizeof(unsigned);
    int*      bin     = (int*)w;      w += (size_t)E * sizeof(int);
    int*      col_idx = (int*)w;      w += (size_t)E * sizeof(int);
    int*      row_ptr = (int*)w;      w += (size_t)(N + 1) * sizeof(int);
    int*      cnt     = (int*)w;      w += (size_t)NB * sizeof(int);
    int*      ptr     = (int*)w;      w += (size_t)(NB + 1) * sizeof(int);
    int*      gcur    = (int*)w;      w += (size_t)NB * sizeof(int);
    float2*   acc_sel = (float2*)w;   w += (size_t)2 * B * 32 * sizeof(float2);

    const int T = 256;
    const int GE = (E + TE - 1) / TE;

    hipMemsetAsync(cnt, 0, (size_t)NB * sizeof(int), stream);
    hipMemsetAsync(acc_sel, 0, (size_t)2 * B * 32 * sizeof(float2), stream);

    // CSR build: LDS-staged counting sort
    bhist_kernel<<<GE, T, 0, stream>>>(rows, cnt, E, NB);
    scan_kernel<<<1, T, 0, stream>>>(cnt, NB, ptr, gcur, row_ptr, N, E);
    split_kernel<<<GE, T, 0, stream>>>(rows, cols, gcur, bin, E, NB);
    csr_kernel<<<NB, T, 0, stream>>>(bin, ptr, row_ptr, col_idx, N);

    // w0 = bf16pack(D^{-1/2} * concat(embeddings))
    w0_kernel<<<(N * 32 + T - 1) / T, T, 0, stream>>>((const float2*)user_emb,
                                                      (const float2*)item_emb,
                                                      row_ptr, x2, U, N);

    // 3 propagation layers (neighbor mean), ping-pong x2<->y2
    unsigned* cur = x2;
    unsigned* nxt = y2;
    for (int layer = 0; layer < NUM_LAYERS; ++layer) {
        spmm_kernel<<<(N * 64 + T - 1) / T, T, 0, stream>>>(row_ptr, col_idx, cur, nxt, N);
        add_sel_kernel<<<(2 * B * 32 + T - 1) / T, T, 0, stream>>>(nxt, user_ids, item_ids,
                                                                   acc_sel, B, U);
        unsigned* tmp = cur; cur = nxt; nxt = tmp;
    }

    dot_kernel<<<(B * 64 + T - 1) / T, T, 0, stream>>>((const float*)acc_sel, row_ptr,
                                                       user_ids, item_ids, out, B, U);
}

// Round 7
// 503.673 us; speedup vs baseline: 2.3732x; 1.0607x over previous
//
#include <hip/hip_runtime.h>

// XSimGCL / LightGCN propagation on MI355X.
// w = D^{-1/2} x  =>  each layer is an unweighted neighbor MEAN; no edge values.
// State stored as packed bf16 pairs (uint = 2 dims) -> 128B rows (r6 win).
// r6 lesson: spmm not HBM-bound (2 of 6.3 TB/s) -> issue/latency-bound.
// This round: octet gathers — each lane loads dwordx4 (16B), 8 lanes/row,
// one wave-gather = 8 edges = 1KB; VMEM instr count /4, addressing VALU /4.
// CSR build stays LDS-staged (r4 lesson: scattered 4B global stores pay ~64B
// HBM writeback each; every global write must be a contiguous run).

#define EMBED_DIM 64
#define NUM_LAYERS 3
#define RSHIFT 8            // 256 rows per bucket
#define RMASK 255
#define NBMAX 640           // supports N <= 163840
#define TE 12288            // edges per tile (fits LDS staging)
#define OUT_CAP 15360       // csr out-staging capacity (avg bucket ~10.2K)

// ---------------- bf16 pair helpers ----------------

__device__ __forceinline__ unsigned bf16pair(float a, float b) {
    unsigned ia = __float_as_uint(a);
    unsigned ib = __float_as_uint(b);
    ia = (ia + 0x7fffu + ((ia >> 16) & 1u)) >> 16;          // RNE, low half
    ib = (ib + 0x7fffu + ((ib >> 16) & 1u)) & 0xffff0000u;  // RNE, high half
    return ia | ib;
}
__device__ __forceinline__ float bf_lo(unsigned u) { return __uint_as_float(u << 16); }
__device__ __forceinline__ float bf_hi(unsigned u) { return __uint_as_float(u & 0xffff0000u); }

// ---------------- bhist: bucket histogram, LDS-aggregated ----------------

__global__ __launch_bounds__(256) void bhist_kernel(const int* __restrict__ rows,
                                                    int* __restrict__ cnt, int E, int NB) {
    __shared__ int h[NBMAX];
    int tid = threadIdx.x;
    for (int i = tid; i < NB; i += 256) h[i] = 0;
    __syncthreads();
    int e0 = blockIdx.x * TE, e1 = min(e0 + TE, E);
    for (int j = e0 + tid; j < e1; j += 256) atomicAdd(&h[rows[j] >> RSHIFT], 1);
    __syncthreads();
    for (int b = tid; b < NB; b += 256)
        if (h[b]) atomicAdd(&cnt[b], h[b]);
}

// ---------------- scan: bucket bases (single block) ----------------

__global__ void scan_kernel(const int* __restrict__ cnt, int NB, int* __restrict__ ptr,
                            int* __restrict__ gcur, int* __restrict__ row_ptr, int N, int E) {
    __shared__ int sc[256];
    int tid = threadIdx.x;
    int carry = 0;
    for (int base = 0; base < NB; base += 256) {
        int i = base + tid;
        int v = (i < NB) ? cnt[i] : 0;
        sc[tid] = v;
        __syncthreads();
        for (int off = 1; off < 256; off <<= 1) {
            int t = (tid >= off) ? sc[tid - off] : 0;
            __syncthreads();
            sc[tid] += t;
            __syncthreads();
        }
        int ex = carry + sc[tid] - v;
        if (i < NB) { ptr[i] = ex; gcur[i] = ex; }
        carry += sc[255];
        __syncthreads();
    }
    if (tid == 0) { ptr[NB] = E; row_ptr[N] = E; }
}

// ---------------- split: tile -> LDS bucket-grouped -> run copies ----------------

__global__ __launch_bounds__(256) void split_kernel(const int* __restrict__ rows,
                                                    const int* __restrict__ cols,
                                                    int* __restrict__ gcur,
                                                    int* __restrict__ bin, int E, int NB) {
    __shared__ int h[NBMAX], exl[NBMAX], curb[NBMAX], gb[NBMAX];
    __shared__ int sc[256];
    __shared__ int stage[TE];
    int tid = threadIdx.x;
    for (int i = tid; i < NB; i += 256) h[i] = 0;
    __syncthreads();
    int e0 = blockIdx.x * TE, e1 = min(e0 + TE, E);
    for (int j = e0 + tid; j < e1; j += 256) atomicAdd(&h[rows[j] >> RSHIFT], 1);
    __syncthreads();
    int carry = 0;
    for (int base = 0; base < NB; base += 256) {
        int i = base + tid;
        int v = (i < NB) ? h[i] : 0;
        sc[tid] = v;
        __syncthreads();
        for (int off = 1; off < 256; off <<= 1) {
            int t = (tid >= off) ? sc[tid - off] : 0;
            __syncthreads();
            sc[tid] += t;
            __syncthreads();
        }
        if (i < NB) exl[i] = carry + sc[tid] - v;
        carry += sc[255];
        __syncthreads();
    }
    for (int b = tid; b < NB; b += 256) {
        curb[b] = exl[b];
        gb[b]   = h[b] ? atomicAdd(&gcur[b], h[b]) : 0;
    }
    __syncthreads();
    for (int j = e0 + tid; j < e1; j += 256) {
        int r = rows[j];
        int b = r >> RSHIFT;
        int pos = atomicAdd(&curb[b], 1);
        stage[pos] = (cols[j] << RSHIFT) | (r & RMASK);
    }
    __syncthreads();
    int wid = tid >> 6, lane = tid & 63;
    for (int b = wid; b < NB; b += 4) {
        int cnt_b = h[b];
        int st = exl[b], g = gb[b];
        for (int k = lane; k < cnt_b; k += 64) bin[g + k] = stage[st + k];
    }
}

// ---------------- csr: per-bucket LDS counting sort ----------------

__global__ __launch_bounds__(256) void csr_kernel(const int* __restrict__ bin,
                                                  const int* __restrict__ ptr,
                                                  int* __restrict__ row_ptr,
                                                  int* __restrict__ col_idx, int N) {
    __shared__ int h2[256], cur2[256];
    __shared__ int outst[OUT_CAP];
    int b   = blockIdx.x;
    int tid = threadIdx.x;
    int s = ptr[b], e = ptr[b + 1];
    int cnt = e - s;
    h2[tid] = 0;
    __syncthreads();
    for (int j = s + tid; j < e; j += 256) atomicAdd(&h2[bin[j] & RMASK], 1);
    __syncthreads();
    cur2[tid] = h2[tid];
    __syncthreads();
    for (int off = 1; off < 256; off <<= 1) {
        int t = (tid >= off) ? cur2[tid - off] : 0;
        __syncthreads();
        cur2[tid] += t;
        __syncthreads();
    }
    cur2[tid] -= h2[tid];  // exclusive
    int gr = (b << RSHIFT) + tid;
    if (gr < N) row_ptr[gr] = s + cur2[tid];
    __syncthreads();
    if (cnt <= OUT_CAP) {
        for (int j = s + tid; j < e; j += 256) {
            int v = bin[j];
            int p = atomicAdd(&cur2[v & RMASK], 1);
            outst[p] = v >> RSHIFT;
        }
        __syncthreads();
        for (int j = tid; j < cnt; j += 256) col_idx[s + j] = outst[j];
    } else {  // safety fallback (never hit at these sizes)
        for (int j = s + tid; j < e; j += 256) {
            int v = bin[j];
            int p = atomicAdd(&cur2[v & RMASK], 1);
            col_idx[s + p] = v >> RSHIFT;
        }
    }
}

// ---------------- w0 = bf16pack(D^{-1/2} * concat(user_emb, item_emb)) ----------------

__global__ void w0_kernel(const float2* __restrict__ ue, const float2* __restrict__ ie,
                          const int* __restrict__ row_ptr, unsigned* __restrict__ w0,
                          int U, int N) {
    int t = blockIdx.x * blockDim.x + threadIdx.x;
    if (t >= N * 32) return;
    int n = t >> 5;
    int d = row_ptr[n + 1] - row_ptr[n];
    float rs = (d > 0) ? rsqrtf((float)d) : 0.0f;
    float2 v = (n < U) ? ue[t] : ie[t - U * 32];
    w0[t] = bf16pair(v.x * rs, v.y * rs);
}

// ---------------- SpMM: neighbor mean, octet gathers (one wave per row) ----------------
// lane = oct*8 + sub: octet handles edge j+oct, sub indexes 16B of the 128B row.
// One gather instr = 8 edges x 128B = 1KB. fp32 accumulate (8 regs/lane),
// 3-round shfl_xor tree over octets, octet 0 packs+stores the bf16 row.

__global__ __launch_bounds__(256) void spmm_kernel(const int* __restrict__ row_ptr,
                                                   const int* __restrict__ col_idx,
                                                   const uint4* __restrict__ x4,
                                                   uint4* __restrict__ y4, int N) {
    int w    = (blockIdx.x * blockDim.x + threadIdx.x) >> 6;
    int lane = threadIdx.x & 63;
    if (w >= N) return;
    int s = row_ptr[w];
    int e = row_ptr[w + 1];
    int oct = lane >> 3;
    int sub = lane & 7;
    float a0 = 0, a1 = 0, a2 = 0, a3 = 0, a4 = 0, a5 = 0, a6 = 0, a7 = 0;
    for (int j = s; j < e; j += 8) {
        int jj = j + oct;
        bool valid = jj < e;
        int c = col_idx[valid ? jj : (e - 1)];
        uint4 u = x4[(unsigned)c * 8u + sub];
        if (!valid) { u.x = 0; u.y = 0; u.z = 0; u.w = 0; }
        a0 += bf_lo(u.x); a1 += bf_hi(u.x);
        a2 += bf_lo(u.y); a3 += bf_hi(u.y);
        a4 += bf_lo(u.z); a5 += bf_hi(u.z);
        a6 += bf_lo(u.w); a7 += bf_hi(u.w);
    }
#pragma unroll
    for (int off = 8; off < 64; off <<= 1) {
        a0 += __shfl_xor(a0, off, 64);
        a1 += __shfl_xor(a1, off, 64);
        a2 += __shfl_xor(a2, off, 64);
        a3 += __shfl_xor(a3, off, 64);
        a4 += __shfl_xor(a4, off, 64);
        a5 += __shfl_xor(a5, off, 64);
        a6 += __shfl_xor(a6, off, 64);
        a7 += __shfl_xor(a7, off, 64);
    }
    if (oct == 0) {
        float inv = (e > s) ? (1.0f / (float)(e - s)) : 0.0f;
        uint4 o;
        o.x = bf16pair(a0 * inv, a1 * inv);
        o.y = bf16pair(a2 * inv, a3 * inv);
        o.z = bf16pair(a4 * inv, a5 * inv);
        o.w = bf16pair(a6 * inv, a7 * inv);
        y4[(size_t)w * 8 + sub] = o;
    }
}

// ---------------- readout ----------------

__global__ void add_sel_kernel(const unsigned* __restrict__ y2, const int* __restrict__ user_ids,
                               const int* __restrict__ item_ids, float2* __restrict__ acc_sel,
                               int B, int U) {
    int t = blockIdx.x * blockDim.x + threadIdx.x;
    if (t >= 2 * B * 32) return;
    int w = t >> 5, sub = t & 31;
    int row = (w < B) ? user_ids[w] : (item_ids[w - B] + U);
    unsigned u = y2[(size_t)row * 32 + sub];
    float2 a = acc_sel[t];
    a.x += bf_lo(u);
    a.y += bf_hi(u);
    acc_sel[t] = a;
}

// out[b] = sqrt(du)*sqrt(di) * dot(accU[b], accI[b]) / 9
__global__ void dot_kernel(const float* __restrict__ acc_sel, const int* __restrict__ row_ptr,
                           const int* __restrict__ user_ids, const int* __restrict__ item_ids,
                           float* __restrict__ out, int B, int U) {
    int w    = (blockIdx.x * blockDim.x + threadIdx.x) >> 6;
    int lane = threadIdx.x & 63;
    if (w >= B) return;
    float p = acc_sel[(size_t)w * EMBED_DIM + lane] * acc_sel[(size_t)(B + w) * EMBED_DIM + lane];
#pragma unroll
    for (int off = 32; off > 0; off >>= 1) p += __shfl_down(p, off, 64);
    if (lane == 0) {
        int ur = user_ids[w];
        int ir = item_ids[w] + U;
        float du = (float)(row_ptr[ur + 1] - row_ptr[ur]);
        float di = (float)(row_ptr[ir + 1] - row_ptr[ir]);
        out[w] = p * sqrtf(du) * sqrtf(di) * (1.0f / (NUM_LAYERS * NUM_LAYERS));
    }
}

// ---------------- launch ----------------

extern "C" void kernel_launch(void* const* d_in, const int* in_sizes, int n_in,
                              void* d_out, int out_size, void* d_ws, size_t ws_size,
                              hipStream_t stream) {
    const float* user_emb = (const float*)d_in[0];
    const float* item_emb = (const float*)d_in[1];
    // d_in[2] (vals) unused: reconstructed algebraically from degrees
    const int*   rows     = (const int*)d_in[3];
    const int*   cols     = (const int*)d_in[4];
    const int*   user_ids = (const int*)d_in[5];
    const int*   item_ids = (const int*)d_in[6];
    float*       out      = (float*)d_out;

    const int U = in_sizes[0] / EMBED_DIM;
    const int I = in_sizes[1] / EMBED_DIM;
    const int E = in_sizes[2];
    const int B = in_sizes[5];
    const int N = U + I;
    const int NB = (N + RMASK) >> RSHIFT;   // 256-row buckets

    // workspace layout
    char* w = (char*)d_ws;
    unsigned* x2      = (unsigned*)w; w += (size_t)N * 32 * sizeof(unsigned);
    unsigned* y2      = (unsigned*)w; w += (size_t)N * 32 * sizeof(unsigned);
    int*      bin     = (int*)w;      w += (size_t)E * sizeof(int);
    int*      col_idx = (int*)w;      w += (size_t)E * sizeof(int);
    int*      row_ptr = (int*)w;      w += (size_t)(N + 1) * sizeof(int);
    int*      cnt     = (int*)w;      w += (size_t)NB * sizeof(int);
    int*      ptr     = (int*)w;      w += (size_t)(NB + 1) * sizeof(int);
    int*      gcur    = (int*)w;      w += (size_t)NB * sizeof(int);
    float2*   acc_sel = (float2*)w;   w += (size_t)2 * B * 32 * sizeof(float2);

    const int T = 256;
    const int GE = (E + TE - 1) / TE;

    hipMemsetAsync(cnt, 0, (size_t)NB * sizeof(int), stream);
    hipMemsetAsync(acc_sel, 0, (size_t)2 * B * 32 * sizeof(float2), stream);

    // CSR build: LDS-staged counting sort
    bhist_kernel<<<GE, T, 0, stream>>>(rows, cnt, E, NB);
    scan_kernel<<<1, T, 0, stream>>>(cnt, NB, ptr, gcur, row_ptr, N, E);
    split_kernel<<<GE, T, 0, stream>>>(rows, cols, gcur, bin, E, NB);
    csr_kernel<<<NB, T, 0, stream>>>(bin, ptr, row_ptr, col_idx, N);

    // w0 = bf16pack(D^{-1/2} * concat(embeddings))
    w0_kernel<<<(N * 32 + T - 1) / T, T, 0, stream>>>((const float2*)user_emb,
                                                      (const float2*)item_emb,
                                                      row_ptr, x2, U, N);

    // 3 propagation layers (neighbor mean), ping-pong x2<->y2
    unsigned* cur = x2;
    unsigned* nxt = y2;
    for (int layer = 0; layer < NUM_LAYERS; ++layer) {
        spmm_kernel<<<(N * 64 + T - 1) / T, T, 0, stream>>>(row_ptr, col_idx,
                                                            (const uint4*)cur, (uint4*)nxt, N);
        add_sel_kernel<<<(2 * B * 32 + T - 1) / T, T, 0, stream>>>(nxt, user_ids, item_ids,
                                                                   acc_sel, B, U);
        unsigned* tmp = cur; cur = nxt; nxt = tmp;
    }

    dot_kernel<<<(B * 64 + T - 1) / T, T, 0, stream>>>((const float*)acc_sel, row_ptr,
                                                       user_ids, item_ids, out, B, U);
}

// Round 8
// 479.596 us; speedup vs baseline: 2.4923x; 1.0502x over previous
//
#include <hip/hip_runtime.h>

// XSimGCL / LightGCN propagation on MI355X.
// w = D^{-1/2} x  =>  each layer is an unweighted neighbor MEAN; no edge values.
// State = packed bf16 pairs, 128B rows. spmm = octet gathers (dwordx4 x 8 lanes
// = 8 edges / wave instr). r7 lesson: spmm is gather-service + unpack bound
// (~85us/layer plateau). r8: exploit symmetrized input (rows=[u;v'], cols=[v';u])
// to read only base pairs in build; single fused readout (3 layer buffers);
// float2 accumulators for v_pk_add_f32.
// CSR build stays LDS-staged (r4: scattered 4B global stores pay ~64B HBM
// writeback each; every global write must be a contiguous run).

#define EMBED_DIM 64
#define NUM_LAYERS 3
#define RSHIFT 8            // 256 rows per bucket
#define RMASK 255
#define NBMAX 640           // supports N <= 163840
#define TP 6144             // base pairs per tile -> 2*TP staged entries
#define OUT_CAP 15360       // csr out-staging capacity (avg bucket ~10.2K)

// ---------------- bf16 pair helpers ----------------

__device__ __forceinline__ unsigned bf16pair(float a, float b) {
    unsigned ia = __float_as_uint(a);
    unsigned ib = __float_as_uint(b);
    ia = (ia + 0x7fffu + ((ia >> 16) & 1u)) >> 16;          // RNE, low half
    ib = (ib + 0x7fffu + ((ib >> 16) & 1u)) & 0xffff0000u;  // RNE, high half
    return ia | ib;
}
__device__ __forceinline__ float bf_lo(unsigned u) { return __uint_as_float(u << 16); }
__device__ __forceinline__ float bf_hi(unsigned u) { return __uint_as_float(u & 0xffff0000u); }

// ---------------- bhist: bucket histogram over BOTH directions ----------------

__global__ __launch_bounds__(256) void bhist_kernel(const int* __restrict__ uu,
                                                    const int* __restrict__ vv,
                                                    int* __restrict__ cnt, int E2, int NB) {
    __shared__ int h[NBMAX];
    int tid = threadIdx.x;
    for (int i = tid; i < NB; i += 256) h[i] = 0;
    __syncthreads();
    int e0 = blockIdx.x * TP, e1 = min(e0 + TP, E2);
    for (int j = e0 + tid; j < e1; j += 256) {
        atomicAdd(&h[uu[j] >> RSHIFT], 1);
        atomicAdd(&h[vv[j] >> RSHIFT], 1);
    }
    __syncthreads();
    for (int b = tid; b < NB; b += 256)
        if (h[b]) atomicAdd(&cnt[b], h[b]);
}

// ---------------- scan: bucket bases (single block) ----------------

__global__ void scan_kernel(const int* __restrict__ cnt, int NB, int* __restrict__ ptr,
                            int* __restrict__ gcur, int* __restrict__ row_ptr, int N, int E) {
    __shared__ int sc[256];
    int tid = threadIdx.x;
    int carry = 0;
    for (int base = 0; base < NB; base += 256) {
        int i = base + tid;
        int v = (i < NB) ? cnt[i] : 0;
        sc[tid] = v;
        __syncthreads();
        for (int off = 1; off < 256; off <<= 1) {
            int t = (tid >= off) ? sc[tid - off] : 0;
            __syncthreads();
            sc[tid] += t;
            __syncthreads();
        }
        int ex = carry + sc[tid] - v;
        if (i < NB) { ptr[i] = ex; gcur[i] = ex; }
        carry += sc[255];
        __syncthreads();
    }
    if (tid == 0) { ptr[NB] = E; row_ptr[N] = E; }
}

// ---------------- split: pairs -> 2 entries -> LDS bucket-grouped -> run copies ----------------

__global__ __launch_bounds__(256) void split_kernel(const int* __restrict__ uu,
                                                    const int* __restrict__ vv,
                                                    int* __restrict__ gcur,
                                                    int* __restrict__ bin, int E2, int NB) {
    __shared__ int h[NBMAX], exl[NBMAX], curb[NBMAX], gb[NBMAX];
    __shared__ int sc[256];
    __shared__ int stage[2 * TP];
    int tid = threadIdx.x;
    for (int i = tid; i < NB; i += 256) h[i] = 0;
    __syncthreads();
    int e0 = blockIdx.x * TP, e1 = min(e0 + TP, E2);
    for (int j = e0 + tid; j < e1; j += 256) {
        atomicAdd(&h[uu[j] >> RSHIFT], 1);
        atomicAdd(&h[vv[j] >> RSHIFT], 1);
    }
    __syncthreads();
    int carry = 0;
    for (int base = 0; base < NB; base += 256) {
        int i = base + tid;
        int v = (i < NB) ? h[i] : 0;
        sc[tid] = v;
        __syncthreads();
        for (int off = 1; off < 256; off <<= 1) {
            int t = (tid >= off) ? sc[tid - off] : 0;
            __syncthreads();
            sc[tid] += t;
            __syncthreads();
        }
        if (i < NB) exl[i] = carry + sc[tid] - v;
        carry += sc[255];
        __syncthreads();
    }
    for (int b = tid; b < NB; b += 256) {
        curb[b] = exl[b];
        gb[b]   = h[b] ? atomicAdd(&gcur[b], h[b]) : 0;
    }
    __syncthreads();
    for (int j = e0 + tid; j < e1; j += 256) {
        int u = uu[j], v = vv[j];
        int p1 = atomicAdd(&curb[u >> RSHIFT], 1);
        stage[p1] = (v << RSHIFT) | (u & RMASK);
        int p2 = atomicAdd(&curb[v >> RSHIFT], 1);
        stage[p2] = (u << RSHIFT) | (v & RMASK);
    }
    __syncthreads();
    int wid = tid >> 6, lane = tid & 63;
    for (int b = wid; b < NB; b += 4) {
        int cnt_b = h[b];
        int st = exl[b], g = gb[b];
        for (int k = lane; k < cnt_b; k += 64) bin[g + k] = stage[st + k];
    }
}

// ---------------- csr: per-bucket LDS counting sort ----------------

__global__ __launch_bounds__(256) void csr_kernel(const int* __restrict__ bin,
                                                  const int* __restrict__ ptr,
                                                  int* __restrict__ row_ptr,
                                                  int* __restrict__ col_idx, int N) {
    __shared__ int h2[256], cur2[256];
    __shared__ int outst[OUT_CAP];
    int b   = blockIdx.x;
    int tid = threadIdx.x;
    int s = ptr[b], e = ptr[b + 1];
    int cnt = e - s;
    h2[tid] = 0;
    __syncthreads();
    for (int j = s + tid; j < e; j += 256) atomicAdd(&h2[bin[j] & RMASK], 1);
    __syncthreads();
    cur2[tid] = h2[tid];
    __syncthreads();
    for (int off = 1; off < 256; off <<= 1) {
        int t = (tid >= off) ? cur2[tid - off] : 0;
        __syncthreads();
        cur2[tid] += t;
        __syncthreads();
    }
    cur2[tid] -= h2[tid];  // exclusive
    int gr = (b << RSHIFT) + tid;
    if (gr < N) row_ptr[gr] = s + cur2[tid];
    __syncthreads();
    if (cnt <= OUT_CAP) {
        for (int j = s + tid; j < e; j += 256) {
            int v = bin[j];
            int p = atomicAdd(&cur2[v & RMASK], 1);
            outst[p] = v >> RSHIFT;
        }
        __syncthreads();
        for (int j = tid; j < cnt; j += 256) col_idx[s + j] = outst[j];
    } else {  // safety fallback (never hit at these sizes)
        for (int j = s + tid; j < e; j += 256) {
            int v = bin[j];
            int p = atomicAdd(&cur2[v & RMASK], 1);
            col_idx[s + p] = v >> RSHIFT;
        }
    }
}

// ---------------- w0 = bf16pack(D^{-1/2} * concat(user_emb, item_emb)) ----------------

__global__ void w0_kernel(const float2* __restrict__ ue, const float2* __restrict__ ie,
                          const int* __restrict__ row_ptr, unsigned* __restrict__ w0,
                          int U, int N) {
    int t = blockIdx.x * blockDim.x + threadIdx.x;
    if (t >= N * 32) return;
    int n = t >> 5;
    int d = row_ptr[n + 1] - row_ptr[n];
    float rs = (d > 0) ? rsqrtf((float)d) : 0.0f;
    float2 v = (n < U) ? ue[t] : ie[t - U * 32];
    w0[t] = bf16pair(v.x * rs, v.y * rs);
}

// ---------------- SpMM: neighbor mean, octet gathers (one wave per row) ----------------

__global__ __launch_bounds__(256) void spmm_kernel(const int* __restrict__ row_ptr,
                                                   const int* __restrict__ col_idx,
                                                   const uint4* __restrict__ x4,
                                                   uint4* __restrict__ y4, int N) {
    int w    = (blockIdx.x * blockDim.x + threadIdx.x) >> 6;
    int lane = threadIdx.x & 63;
    if (w >= N) return;
    int s = row_ptr[w];
    int e = row_ptr[w + 1];
    int oct = lane >> 3;
    int sub = lane & 7;
    float2 a0 = {0, 0}, a1 = {0, 0}, a2 = {0, 0}, a3 = {0, 0};
    for (int j = s; j < e; j += 8) {
        int jj = j + oct;
        bool valid = jj < e;
        int c = col_idx[valid ? jj : (e - 1)];
        uint4 u = x4[(unsigned)c * 8u + sub];
        if (!valid) { u.x = 0; u.y = 0; u.z = 0; u.w = 0; }
        a0.x += bf_lo(u.x); a0.y += bf_hi(u.x);
        a1.x += bf_lo(u.y); a1.y += bf_hi(u.y);
        a2.x += bf_lo(u.z); a2.y += bf_hi(u.z);
        a3.x += bf_lo(u.w); a3.y += bf_hi(u.w);
    }
#pragma unroll
    for (int off = 8; off < 64; off <<= 1) {
        a0.x += __shfl_xor(a0.x, off, 64); a0.y += __shfl_xor(a0.y, off, 64);
        a1.x += __shfl_xor(a1.x, off, 64); a1.y += __shfl_xor(a1.y, off, 64);
        a2.x += __shfl_xor(a2.x, off, 64); a2.y += __shfl_xor(a2.y, off, 64);
        a3.x += __shfl_xor(a3.x, off, 64); a3.y += __shfl_xor(a3.y, off, 64);
    }
    if (oct == 0) {
        float inv = (e > s) ? (1.0f / (float)(e - s)) : 0.0f;
        uint4 o;
        o.x = bf16pair(a0.x * inv, a0.y * inv);
        o.y = bf16pair(a1.x * inv, a1.y * inv);
        o.z = bf16pair(a2.x * inv, a2.y * inv);
        o.w = bf16pair(a3.x * inv, a3.y * inv);
        y4[(size_t)w * 8 + sub] = o;
    }
}

// ---------------- fused readout ----------------
// one wave per batch element: lanes 0-31 sum user row across 3 layer buffers,
// lanes 32-63 item row; cross-half shfl pairs them; dot-reduce; lane 0 writes
// out[b] = sqrt(du)*sqrt(di)/9 * dot.

__global__ __launch_bounds__(256) void readout_kernel(const unsigned* __restrict__ l1,
                                                      const unsigned* __restrict__ l2,
                                                      const unsigned* __restrict__ l3,
                                                      const int* __restrict__ row_ptr,
                                                      const int* __restrict__ user_ids,
                                                      const int* __restrict__ item_ids,
                                                      float* __restrict__ out, int B, int U) {
    int b    = (blockIdx.x * blockDim.x + threadIdx.x) >> 6;
    int lane = threadIdx.x & 63;
    if (b >= B) return;
    int half = lane >> 5, sub = lane & 31;
    int row = half ? (item_ids[b] + U) : user_ids[b];
    size_t idx = (size_t)row * 32 + sub;
    unsigned u1 = l1[idx], u2 = l2[idx], u3 = l3[idx];
    float sx = bf_lo(u1) + bf_lo(u2) + bf_lo(u3);
    float sy = bf_hi(u1) + bf_hi(u2) + bf_hi(u3);
    float ox = __shfl_xor(sx, 32, 64);
    float oy = __shfl_xor(sy, 32, 64);
    float p = sx * ox + sy * oy;   // valid on lanes 0-31 (user*item)
#pragma unroll
    for (int off = 16; off > 0; off >>= 1) p += __shfl_down(p, off, 64);
    if (lane == 0) {
        int ur = user_ids[b];
        int ir = item_ids[b] + U;
        float du = (float)(row_ptr[ur + 1] - row_ptr[ur]);
        float di = (float)(row_ptr[ir + 1] - row_ptr[ir]);
        out[b] = p * sqrtf(du) * sqrtf(di) * (1.0f / (NUM_LAYERS * NUM_LAYERS));
    }
}

// ---------------- launch ----------------

extern "C" void kernel_launch(void* const* d_in, const int* in_sizes, int n_in,
                              void* d_out, int out_size, void* d_ws, size_t ws_size,
                              hipStream_t stream) {
    const float* user_emb = (const float*)d_in[0];
    const float* item_emb = (const float*)d_in[1];
    // d_in[2] (vals) unused: reconstructed algebraically from degrees
    const int*   rows     = (const int*)d_in[3];
    const int*   cols     = (const int*)d_in[4];
    const int*   user_ids = (const int*)d_in[5];
    const int*   item_ids = (const int*)d_in[6];
    float*       out      = (float*)d_out;

    const int U = in_sizes[0] / EMBED_DIM;
    const int I = in_sizes[1] / EMBED_DIM;
    const int E = in_sizes[3];          // directed edges
    const int E2 = E >> 1;              // base pairs: rows=[u;v'], cols=[v';u]
    const int B = in_sizes[5];
    const int N = U + I;
    const int NB = (N + RMASK) >> RSHIFT;   // 256-row buckets

    // workspace layout
    char* w = (char*)d_ws;
    unsigned* x2      = (unsigned*)w; w += (size_t)N * 32 * sizeof(unsigned);
    unsigned* L1      = (unsigned*)w; w += (size_t)N * 32 * sizeof(unsigned);
    unsigned* L2      = (unsigned*)w; w += (size_t)N * 32 * sizeof(unsigned);
    unsigned* L3      = (unsigned*)w; w += (size_t)N * 32 * sizeof(unsigned);
    int*      bin     = (int*)w;      w += (size_t)E * sizeof(int);
    int*      col_idx = (int*)w;      w += (size_t)E * sizeof(int);
    int*      row_ptr = (int*)w;      w += (size_t)(N + 1) * sizeof(int);
    int*      cnt     = (int*)w;      w += (size_t)NB * sizeof(int);
    int*      ptr     = (int*)w;      w += (size_t)(NB + 1) * sizeof(int);
    int*      gcur    = (int*)w;      w += (size_t)NB * sizeof(int);

    const int T = 256;
    const int GP = (E2 + TP - 1) / TP;

    hipMemsetAsync(cnt, 0, (size_t)NB * sizeof(int), stream);

    // CSR build: LDS-staged counting sort, mirror-edge input (read base pairs only)
    bhist_kernel<<<GP, T, 0, stream>>>(rows, cols, cnt, E2, NB);
    scan_kernel<<<1, T, 0, stream>>>(cnt, NB, ptr, gcur, row_ptr, N, E);
    split_kernel<<<GP, T, 0, stream>>>(rows, cols, gcur, bin, E2, NB);
    csr_kernel<<<NB, T, 0, stream>>>(bin, ptr, row_ptr, col_idx, N);

    // w0 = bf16pack(D^{-1/2} * concat(embeddings))
    w0_kernel<<<(N * 32 + T - 1) / T, T, 0, stream>>>((const float2*)user_emb,
                                                      (const float2*)item_emb,
                                                      row_ptr, x2, U, N);

    // 3 propagation layers (neighbor mean), separate outputs for fused readout
    spmm_kernel<<<(N * 64 + T - 1) / T, T, 0, stream>>>(row_ptr, col_idx,
                                                        (const uint4*)x2, (uint4*)L1, N);
    spmm_kernel<<<(N * 64 + T - 1) / T, T, 0, stream>>>(row_ptr, col_idx,
                                                        (const uint4*)L1, (uint4*)L2, N);
    spmm_kernel<<<(N * 64 + T - 1) / T, T, 0, stream>>>(row_ptr, col_idx,
                                                        (const uint4*)L2, (uint4*)L3, N);

    readout_kernel<<<(B * 64 + T - 1) / T, T, 0, stream>>>(L1, L2, L3, row_ptr,
                                                           user_ids, item_ids, out, B, U);
}

// Round 11
// 420.992 us; speedup vs baseline: 2.8393x; 1.1392x over previous
//
#include <hip/hip_runtime.h>

// XSimGCL / LightGCN propagation on MI355X.
// w = D^{-1/2} x  =>  each layer is an unweighted neighbor MEAN; no edge values.
// State = packed bf16 pairs, 128B rows. spmm = dual octet gathers (16 edges in
// flight per wave iter). Build: fixed-capacity buckets, NO global hist/scan.
// r10 lesson (crash root cause): bucket load is BIMODAL — user buckets mean
// 5120, item buckets mean 10240; a single CAP=8192 overflowed item buckets.
// Now: buckets < BSPLIT (pure users) CAPU=8192 (~42 sigma), >= BSPLIT (items)
// CAPI=12288 (~20 sigma). base(b) = min(b,BSPLIT)*CAPU + max(b-BSPLIT,0)*CAPI.
// r4 lesson: scattered 4B global stores pay ~64B HBM writeback each; every
// global write is a contiguous run staged through LDS.

#define EMBED_DIM 64
#define NUM_LAYERS 3
#define RSHIFT 8            // 256 rows per bucket
#define RMASK 255
#define NBMAX 640           // supports N <= 163840
#define CAPU 8192           // user-bucket capacity (mean 5120)
#define CAPI 12288          // item-bucket capacity (mean 10240)
#define TP 6144             // base pairs per tile -> 2*TP staged entries
#define OUT_CAP 15360       // csr out-staging capacity (>= CAPI)

__device__ __forceinline__ int bucket_base(int b, int BSPLIT) {
    int lo = (b < BSPLIT) ? b : BSPLIT;
    int hi = (b > BSPLIT) ? (b - BSPLIT) : 0;
    return lo * CAPU + hi * CAPI;
}

// ---------------- bf16 pair helpers ----------------

__device__ __forceinline__ unsigned bf16pair(float a, float b) {
    unsigned ia = __float_as_uint(a);
    unsigned ib = __float_as_uint(b);
    ia = (ia + 0x7fffu + ((ia >> 16) & 1u)) >> 16;          // RNE, low half
    ib = (ib + 0x7fffu + ((ib >> 16) & 1u)) & 0xffff0000u;  // RNE, high half
    return ia | ib;
}
__device__ __forceinline__ float bf_lo(unsigned u) { return __uint_as_float(u << 16); }
__device__ __forceinline__ float bf_hi(unsigned u) { return __uint_as_float(u & 0xffff0000u); }

// ---------------- init: gcur[b] = bucket_base(b) ----------------

__global__ void init_gcur_kernel(int* __restrict__ gcur, int NB, int BSPLIT) {
    int b = blockIdx.x * blockDim.x + threadIdx.x;
    if (b < NB) gcur[b] = bucket_base(b, BSPLIT);
}

// ---------------- split: pairs -> 2 entries -> LDS bucket-grouped -> run copies ----------------

__global__ __launch_bounds__(256) void split_kernel(const int* __restrict__ uu,
                                                    const int* __restrict__ vv,
                                                    int* __restrict__ gcur,
                                                    int* __restrict__ bin, int E2, int NB) {
    __shared__ int h[NBMAX], exl[NBMAX], curb[NBMAX], gb[NBMAX];
    __shared__ int sc[256];
    __shared__ int stage[2 * TP];
    int tid = threadIdx.x;
    for (int i = tid; i < NB; i += 256) h[i] = 0;
    __syncthreads();
    int e0 = blockIdx.x * TP, e1 = min(e0 + TP, E2);
    for (int j = e0 + tid; j < e1; j += 256) {
        atomicAdd(&h[uu[j] >> RSHIFT], 1);
        atomicAdd(&h[vv[j] >> RSHIFT], 1);
    }
    __syncthreads();
    // tile-local exclusive scan of h -> exl (LDS staging offsets)
    int carry = 0;
    for (int base = 0; base < NB; base += 256) {
        int i = base + tid;
        int v = (i < NB) ? h[i] : 0;
        sc[tid] = v;
        __syncthreads();
        for (int off = 1; off < 256; off <<= 1) {
            int t = (tid >= off) ? sc[tid - off] : 0;
            __syncthreads();
            sc[tid] += t;
            __syncthreads();
        }
        if (i < NB) exl[i] = carry + sc[tid] - v;
        carry += sc[255];
        __syncthreads();
    }
    for (int b = tid; b < NB; b += 256) {
        curb[b] = exl[b];
        gb[b]   = h[b] ? atomicAdd(&gcur[b], h[b]) : 0;
    }
    __syncthreads();
    for (int j = e0 + tid; j < e1; j += 256) {
        int u = uu[j], v = vv[j];
        int p1 = atomicAdd(&curb[u >> RSHIFT], 1);
        stage[p1] = (v << RSHIFT) | (u & RMASK);
        int p2 = atomicAdd(&curb[v >> RSHIFT], 1);
        stage[p2] = (u << RSHIFT) | (v & RMASK);
    }
    __syncthreads();
    int wid = tid >> 6, lane = tid & 63;
    for (int b = wid; b < NB; b += 4) {
        int cnt_b = h[b];
        int st = exl[b], g = gb[b];
        for (int k = lane; k < cnt_b; k += 64) bin[g + k] = stage[st + k];
    }
}

// ---------------- csr: per-bucket LDS counting sort -> row_ptr, deg, col_idx ----------------

__global__ __launch_bounds__(256) void csr_kernel(const int* __restrict__ bin,
                                                  const int* __restrict__ gcur,
                                                  int* __restrict__ row_ptr,
                                                  int* __restrict__ deg,
                                                  int* __restrict__ col_idx, int N, int BSPLIT) {
    __shared__ int h2[256], cur2[256];
    __shared__ int outst[OUT_CAP];
    int b   = blockIdx.x;
    int tid = threadIdx.x;
    int s = bucket_base(b, BSPLIT);
    int e = gcur[b];          // == s + bucket count (after split)
    int cnt = e - s;
    h2[tid] = 0;
    __syncthreads();
    for (int j = s + tid; j < e; j += 256) atomicAdd(&h2[bin[j] & RMASK], 1);
    __syncthreads();
    cur2[tid] = h2[tid];
    __syncthreads();
    for (int off = 1; off < 256; off <<= 1) {
        int t = (tid >= off) ? cur2[tid - off] : 0;
        __syncthreads();
        cur2[tid] += t;
        __syncthreads();
    }
    cur2[tid] -= h2[tid];  // exclusive within bucket
    int gr = (b << RSHIFT) + tid;
    if (gr < N) {
        row_ptr[gr] = s + cur2[tid];
        deg[gr]     = h2[tid];
    }
    __syncthreads();
    if (cnt <= OUT_CAP) {
        for (int j = s + tid; j < e; j += 256) {
            int v = bin[j];
            int p = atomicAdd(&cur2[v & RMASK], 1);
            outst[p] = v >> RSHIFT;
        }
        __syncthreads();
        for (int j = tid; j < cnt; j += 256) col_idx[s + j] = outst[j];
    } else {  // safety fallback
        for (int j = s + tid; j < e; j += 256) {
            int v = bin[j];
            int p = atomicAdd(&cur2[v & RMASK], 1);
            col_idx[s + p] = v >> RSHIFT;
        }
    }
}

// ---------------- w0 = bf16pack(D^{-1/2} * concat(user_emb, item_emb)) ----------------

__global__ void w0_kernel(const float2* __restrict__ ue, const float2* __restrict__ ie,
                          const int* __restrict__ deg, unsigned* __restrict__ w0,
                          int U, int N) {
    int t = blockIdx.x * blockDim.x + threadIdx.x;
    if (t >= N * 32) return;
    int n = t >> 5;
    int d = deg[n];
    float rs = (d > 0) ? rsqrtf((float)d) : 0.0f;
    float2 v = (n < U) ? ue[t] : ie[t - U * 32];
    w0[t] = bf16pair(v.x * rs, v.y * rs);
}

// ---------------- SpMM: neighbor mean, dual octet gathers (one wave per row) ----------------

__global__ __launch_bounds__(256) void spmm_kernel(const int* __restrict__ row_ptr,
                                                   const int* __restrict__ deg,
                                                   const int* __restrict__ col_idx,
                                                   const uint4* __restrict__ x4,
                                                   uint4* __restrict__ y4, int N) {
    int w    = (blockIdx.x * blockDim.x + threadIdx.x) >> 6;
    int lane = threadIdx.x & 63;
    if (w >= N) return;
    int s = row_ptr[w];
    int d = deg[w];
    int e = s + d;
    int oct = lane >> 3;
    int sub = lane & 7;
    float2 a0 = {0, 0}, a1 = {0, 0}, a2 = {0, 0}, a3 = {0, 0};
    for (int j = s; j < e; j += 16) {
        int jj0 = j + oct;
        int jj1 = jj0 + 8;
        bool v0 = jj0 < e;
        bool v1 = jj1 < e;
        int c0 = col_idx[v0 ? jj0 : (e - 1)];
        int c1 = col_idx[v1 ? jj1 : (e - 1)];
        uint4 u0 = x4[(unsigned)c0 * 8u + sub];
        uint4 u1 = x4[(unsigned)c1 * 8u + sub];
        if (!v0) { u0.x = 0; u0.y = 0; u0.z = 0; u0.w = 0; }
        if (!v1) { u1.x = 0; u1.y = 0; u1.z = 0; u1.w = 0; }
        a0.x += bf_lo(u0.x); a0.y += bf_hi(u0.x);
        a1.x += bf_lo(u0.y); a1.y += bf_hi(u0.y);
        a2.x += bf_lo(u0.z); a2.y += bf_hi(u0.z);
        a3.x += bf_lo(u0.w); a3.y += bf_hi(u0.w);
        a0.x += bf_lo(u1.x); a0.y += bf_hi(u1.x);
        a1.x += bf_lo(u1.y); a1.y += bf_hi(u1.y);
        a2.x += bf_lo(u1.z); a2.y += bf_hi(u1.z);
        a3.x += bf_lo(u1.w); a3.y += bf_hi(u1.w);
    }
#pragma unroll
    for (int off = 8; off < 64; off <<= 1) {
        a0.x += __shfl_xor(a0.x, off, 64); a0.y += __shfl_xor(a0.y, off, 64);
        a1.x += __shfl_xor(a1.x, off, 64); a1.y += __shfl_xor(a1.y, off, 64);
        a2.x += __shfl_xor(a2.x, off, 64); a2.y += __shfl_xor(a2.y, off, 64);
        a3.x += __shfl_xor(a3.x, off, 64); a3.y += __shfl_xor(a3.y, off, 64);
    }
    if (oct == 0) {
        float inv = (d > 0) ? (1.0f / (float)d) : 0.0f;
        uint4 o;
        o.x = bf16pair(a0.x * inv, a0.y * inv);
        o.y = bf16pair(a1.x * inv, a1.y * inv);
        o.z = bf16pair(a2.x * inv, a2.y * inv);
        o.w = bf16pair(a3.x * inv, a3.y * inv);
        y4[(size_t)w * 8 + sub] = o;
    }
}

// ---------------- fused readout ----------------

__global__ __launch_bounds__(256) void readout_kernel(const unsigned* __restrict__ l1,
                                                      const unsigned* __restrict__ l2,
                                                      const unsigned* __restrict__ l3,
                                                      const int* __restrict__ deg,
                                                      const int* __restrict__ user_ids,
                                                      const int* __restrict__ item_ids,
                                                      float* __restrict__ out, int B, int U) {
    int b    = (blockIdx.x * blockDim.x + threadIdx.x) >> 6;
    int lane = threadIdx.x & 63;
    if (b >= B) return;
    int half = lane >> 5, sub = lane & 31;
    int row = half ? (item_ids[b] + U) : user_ids[b];
    size_t idx = (size_t)row * 32 + sub;
    unsigned u1 = l1[idx], u2 = l2[idx], u3 = l3[idx];
    float sx = bf_lo(u1) + bf_lo(u2) + bf_lo(u3);
    float sy = bf_hi(u1) + bf_hi(u2) + bf_hi(u3);
    float ox = __shfl_xor(sx, 32, 64);
    float oy = __shfl_xor(sy, 32, 64);
    float p = sx * ox + sy * oy;   // lanes 0-31: user*item partial dot
#pragma unroll
    for (int off = 16; off > 0; off >>= 1) p += __shfl_down(p, off, 64);
    if (lane == 0) {
        float du = (float)deg[user_ids[b]];
        float di = (float)deg[item_ids[b] + U];
        out[b] = p * sqrtf(du) * sqrtf(di) * (1.0f / (NUM_LAYERS * NUM_LAYERS));
    }
}

// ---------------- launch ----------------

extern "C" void kernel_launch(void* const* d_in, const int* in_sizes, int n_in,
                              void* d_out, int out_size, void* d_ws, size_t ws_size,
                              hipStream_t stream) {
    const float* user_emb = (const float*)d_in[0];
    const float* item_emb = (const float*)d_in[1];
    // d_in[2] (vals) unused: reconstructed algebraically from degrees
    const int*   rows     = (const int*)d_in[3];
    const int*   cols     = (const int*)d_in[4];
    const int*   user_ids = (const int*)d_in[5];
    const int*   item_ids = (const int*)d_in[6];
    float*       out      = (float*)d_out;

    const int U = in_sizes[0] / EMBED_DIM;
    const int I = in_sizes[1] / EMBED_DIM;
    const int E2 = in_sizes[3] >> 1;    // base pairs: rows=[u;v'], cols=[v';u]
    const int B = in_sizes[5];
    const int N = U + I;
    const int NB = (N + RMASK) >> RSHIFT;   // 256-row buckets
    const int BSPLIT = U >> RSHIFT;         // buckets below: pure users

    // total bin entries = bucket_base(NB)
    const long long TOT = (long long)((NB < BSPLIT ? NB : BSPLIT)) * CAPU +
                          (long long)((NB > BSPLIT) ? (NB - BSPLIT) : 0) * CAPI;

    // workspace layout (~104MB)
    char* w = (char*)d_ws;
    unsigned* x2      = (unsigned*)w; w += (size_t)N * 32 * sizeof(unsigned);   // w0, later L3
    unsigned* L1      = (unsigned*)w; w += (size_t)N * 32 * sizeof(unsigned);
    unsigned* L2      = (unsigned*)w; w += (size_t)N * 32 * sizeof(unsigned);
    int*      bin     = (int*)w;      w += (size_t)TOT * sizeof(int);
    int*      col_idx = (int*)w;      w += (size_t)TOT * sizeof(int);
    int*      row_ptr = (int*)w;      w += (size_t)N * sizeof(int);
    int*      deg     = (int*)w;      w += (size_t)N * sizeof(int);
    int*      gcur    = (int*)w;      w += (size_t)NB * sizeof(int);

    const int T = 256;
    const int GP = (E2 + TP - 1) / TP;

    // CSR build: split-capacity buckets, LDS-staged counting sort
    init_gcur_kernel<<<(NB + T - 1) / T, T, 0, stream>>>(gcur, NB, BSPLIT);
    split_kernel<<<GP, T, 0, stream>>>(rows, cols, gcur, bin, E2, NB);
    csr_kernel<<<NB, T, 0, stream>>>(bin, gcur, row_ptr, deg, col_idx, N, BSPLIT);

    // w0 = bf16pack(D^{-1/2} * concat(embeddings))
    w0_kernel<<<(N * 32 + T - 1) / T, T, 0, stream>>>((const float2*)user_emb,
                                                      (const float2*)item_emb,
                                                      deg, x2, U, N);

    // 3 propagation layers (neighbor mean); layer 3 reuses x2 as output
    spmm_kernel<<<(N * 64 + T - 1) / T, T, 0, stream>>>(row_ptr, deg, col_idx,
                                                        (const uint4*)x2, (uint4*)L1, N);
    spmm_kernel<<<(N * 64 + T - 1) / T, T, 0, stream>>>(row_ptr, deg, col_idx,
                                                        (const uint4*)L1, (uint4*)L2, N);
    spmm_kernel<<<(N * 64 + T - 1) / T, T, 0, stream>>>(row_ptr, deg, col_idx,
                                                        (const uint4*)L2, (uint4*)x2, N);

    readout_kernel<<<(B * 64 + T - 1) / T, T, 0, stream>>>(L1, L2, x2, deg,
                                                           user_ids, item_ids, out, B, U);
}

// Round 12
// 402.123 us; speedup vs baseline: 2.9725x; 1.0469x over previous
//
#include <hip/hip_runtime.h>

// XSimGCL / LightGCN propagation on MI355X.
// w = D^{-1/2} x  =>  each layer is an unweighted neighbor MEAN; no edge values.
// State = packed bf16 pairs, 128B rows.
// r12 spmm: OCTET-PER-ROW — each 8-lane octet owns one row (sub = 16B slice),
// private fp32 accumulation, NO cross-lane reduction (r11 lesson: the 48-instr
// shfl tree was ~45% of spmm VALU at mean degree 27), no clamp gathers,
// contiguous 1KB stores (8 adjacent rows/wave). Unroll-2 keeps 2 gathers in
// flight (r11: MLP win).
// Build: split-capacity buckets (r10 lesson: bucket load BIMODAL — user mean
// 5120, item mean 10240; CAPU=8192/CAPI=12288), no global hist/scan.
// r4 lesson: scattered 4B global stores pay ~64B HBM writeback each; every
// global write is a contiguous run staged through LDS.

#define EMBED_DIM 64
#define NUM_LAYERS 3
#define RSHIFT 8            // 256 rows per bucket
#define RMASK 255
#define NBMAX 640           // supports N <= 163840
#define CAPU 8192           // user-bucket capacity (mean 5120)
#define CAPI 12288          // item-bucket capacity (mean 10240)
#define TP 6144             // base pairs per tile -> 2*TP staged entries
#define OUT_CAP 15360       // csr out-staging capacity (>= CAPI)

__device__ __forceinline__ int bucket_base(int b, int BSPLIT) {
    int lo = (b < BSPLIT) ? b : BSPLIT;
    int hi = (b > BSPLIT) ? (b - BSPLIT) : 0;
    return lo * CAPU + hi * CAPI;
}

// ---------------- bf16 pair helpers ----------------

__device__ __forceinline__ unsigned bf16pair(float a, float b) {
    unsigned ia = __float_as_uint(a);
    unsigned ib = __float_as_uint(b);
    ia = (ia + 0x7fffu + ((ia >> 16) & 1u)) >> 16;          // RNE, low half
    ib = (ib + 0x7fffu + ((ib >> 16) & 1u)) & 0xffff0000u;  // RNE, high half
    return ia | ib;
}
__device__ __forceinline__ float bf_lo(unsigned u) { return __uint_as_float(u << 16); }
__device__ __forceinline__ float bf_hi(unsigned u) { return __uint_as_float(u & 0xffff0000u); }

// ---------------- init: gcur[b] = bucket_base(b) ----------------

__global__ void init_gcur_kernel(int* __restrict__ gcur, int NB, int BSPLIT) {
    int b = blockIdx.x * blockDim.x + threadIdx.x;
    if (b < NB) gcur[b] = bucket_base(b, BSPLIT);
}

// ---------------- split: pairs -> 2 entries -> LDS bucket-grouped -> run copies ----------------

__global__ __launch_bounds__(256) void split_kernel(const int* __restrict__ uu,
                                                    const int* __restrict__ vv,
                                                    int* __restrict__ gcur,
                                                    int* __restrict__ bin, int E2, int NB) {
    __shared__ int h[NBMAX], exl[NBMAX], curb[NBMAX], gb[NBMAX];
    __shared__ int sc[256];
    __shared__ int stage[2 * TP];
    int tid = threadIdx.x;
    for (int i = tid; i < NB; i += 256) h[i] = 0;
    __syncthreads();
    int e0 = blockIdx.x * TP, e1 = min(e0 + TP, E2);
    for (int j = e0 + tid; j < e1; j += 256) {
        atomicAdd(&h[uu[j] >> RSHIFT], 1);
        atomicAdd(&h[vv[j] >> RSHIFT], 1);
    }
    __syncthreads();
    // tile-local exclusive scan of h -> exl (LDS staging offsets)
    int carry = 0;
    for (int base = 0; base < NB; base += 256) {
        int i = base + tid;
        int v = (i < NB) ? h[i] : 0;
        sc[tid] = v;
        __syncthreads();
        for (int off = 1; off < 256; off <<= 1) {
            int t = (tid >= off) ? sc[tid - off] : 0;
            __syncthreads();
            sc[tid] += t;
            __syncthreads();
        }
        if (i < NB) exl[i] = carry + sc[tid] - v;
        carry += sc[255];
        __syncthreads();
    }
    for (int b = tid; b < NB; b += 256) {
        curb[b] = exl[b];
        gb[b]   = h[b] ? atomicAdd(&gcur[b], h[b]) : 0;
    }
    __syncthreads();
    for (int j = e0 + tid; j < e1; j += 256) {
        int u = uu[j], v = vv[j];
        int p1 = atomicAdd(&curb[u >> RSHIFT], 1);
        stage[p1] = (v << RSHIFT) | (u & RMASK);
        int p2 = atomicAdd(&curb[v >> RSHIFT], 1);
        stage[p2] = (u << RSHIFT) | (v & RMASK);
    }
    __syncthreads();
    int wid = tid >> 6, lane = tid & 63;
    for (int b = wid; b < NB; b += 4) {
        int cnt_b = h[b];
        int st = exl[b], g = gb[b];
        for (int k = lane; k < cnt_b; k += 64) bin[g + k] = stage[st + k];
    }
}

// ---------------- csr: per-bucket LDS counting sort -> row_ptr, deg, col_idx ----------------

__global__ __launch_bounds__(256) void csr_kernel(const int* __restrict__ bin,
                                                  const int* __restrict__ gcur,
                                                  int* __restrict__ row_ptr,
                                                  int* __restrict__ deg,
                                                  int* __restrict__ col_idx, int N, int BSPLIT) {
    __shared__ int h2[256], cur2[256];
    __shared__ int outst[OUT_CAP];
    int b   = blockIdx.x;
    int tid = threadIdx.x;
    int s = bucket_base(b, BSPLIT);
    int e = gcur[b];          // == s + bucket count (after split)
    int cnt = e - s;
    h2[tid] = 0;
    __syncthreads();
    for (int j = s + tid; j < e; j += 256) atomicAdd(&h2[bin[j] & RMASK], 1);
    __syncthreads();
    cur2[tid] = h2[tid];
    __syncthreads();
    for (int off = 1; off < 256; off <<= 1) {
        int t = (tid >= off) ? cur2[tid - off] : 0;
        __syncthreads();
        cur2[tid] += t;
        __syncthreads();
    }
    cur2[tid] -= h2[tid];  // exclusive within bucket
    int gr = (b << RSHIFT) + tid;
    if (gr < N) {
        row_ptr[gr] = s + cur2[tid];
        deg[gr]     = h2[tid];
    }
    __syncthreads();
    if (cnt <= OUT_CAP) {
        for (int j = s + tid; j < e; j += 256) {
            int v = bin[j];
            int p = atomicAdd(&cur2[v & RMASK], 1);
            outst[p] = v >> RSHIFT;
        }
        __syncthreads();
        for (int j = tid; j < cnt; j += 256) col_idx[s + j] = outst[j];
    } else {  // safety fallback
        for (int j = s + tid; j < e; j += 256) {
            int v = bin[j];
            int p = atomicAdd(&cur2[v & RMASK], 1);
            col_idx[s + p] = v >> RSHIFT;
        }
    }
}

// ---------------- w0 = bf16pack(D^{-1/2} * concat(user_emb, item_emb)) ----------------

__global__ void w0_kernel(const float2* __restrict__ ue, const float2* __restrict__ ie,
                          const int* __restrict__ deg, unsigned* __restrict__ w0,
                          int U, int N) {
    int t = blockIdx.x * blockDim.x + threadIdx.x;
    if (t >= N * 32) return;
    int n = t >> 5;
    int d = deg[n];
    float rs = (d > 0) ? rsqrtf((float)d) : 0.0f;
    float2 v = (n < U) ? ue[t] : ie[t - U * 32];
    w0[t] = bf16pair(v.x * rs, v.y * rs);
}

// ---------------- SpMM: neighbor mean, octet-per-row ----------------
// Octet o of wave gw owns row r = gw*8+o; its 8 lanes hold the row's 128B
// (sub = 16B slice). Private fp32 accumulation over the row's edges, no
// cross-lane reduction. Per-lane loop bound => no clamp gathers. Unroll-2
// keeps 2 independent 1KB wave-gathers in flight. Store: wave writes 8
// adjacent rows = 1KB contiguous.

__global__ __launch_bounds__(256) void spmm_kernel(const int* __restrict__ row_ptr,
                                                   const int* __restrict__ deg,
                                                   const int* __restrict__ col_idx,
                                                   const uint4* __restrict__ x4,
                                                   uint4* __restrict__ y4, int N) {
    int gw   = (blockIdx.x * blockDim.x + threadIdx.x) >> 6;
    int lane = threadIdx.x & 63;
    int oct  = lane >> 3, sub = lane & 7;
    int r = gw * 8 + oct;
    if (r >= N) return;
    int s = row_ptr[r];
    int d = deg[r];
    float2 a0 = {0, 0}, a1 = {0, 0}, a2 = {0, 0}, a3 = {0, 0};
    int k = 0;
    for (; k + 1 < d; k += 2) {
        int c0 = col_idx[s + k];
        int c1 = col_idx[s + k + 1];
        uint4 u0 = x4[(size_t)c0 * 8 + sub];
        uint4 u1 = x4[(size_t)c1 * 8 + sub];
        a0.x += bf_lo(u0.x); a0.y += bf_hi(u0.x);
        a1.x += bf_lo(u0.y); a1.y += bf_hi(u0.y);
        a2.x += bf_lo(u0.z); a2.y += bf_hi(u0.z);
        a3.x += bf_lo(u0.w); a3.y += bf_hi(u0.w);
        a0.x += bf_lo(u1.x); a0.y += bf_hi(u1.x);
        a1.x += bf_lo(u1.y); a1.y += bf_hi(u1.y);
        a2.x += bf_lo(u1.z); a2.y += bf_hi(u1.z);
        a3.x += bf_lo(u1.w); a3.y += bf_hi(u1.w);
    }
    if (k < d) {
        int c0 = col_idx[s + k];
        uint4 u0 = x4[(size_t)c0 * 8 + sub];
        a0.x += bf_lo(u0.x); a0.y += bf_hi(u0.x);
        a1.x += bf_lo(u0.y); a1.y += bf_hi(u0.y);
        a2.x += bf_lo(u0.z); a2.y += bf_hi(u0.z);
        a3.x += bf_lo(u0.w); a3.y += bf_hi(u0.w);
    }
    float inv = (d > 0) ? (1.0f / (float)d) : 0.0f;
    uint4 o;
    o.x = bf16pair(a0.x * inv, a0.y * inv);
    o.y = bf16pair(a1.x * inv, a1.y * inv);
    o.z = bf16pair(a2.x * inv, a2.y * inv);
    o.w = bf16pair(a3.x * inv, a3.y * inv);
    y4[(size_t)r * 8 + sub] = o;
}

// ---------------- fused readout ----------------

__global__ __launch_bounds__(256) void readout_kernel(const unsigned* __restrict__ l1,
                                                      const unsigned* __restrict__ l2,
                                                      const unsigned* __restrict__ l3,
                                                      const int* __restrict__ deg,
                                                      const int* __restrict__ user_ids,
                                                      const int* __restrict__ item_ids,
                                                      float* __restrict__ out, int B, int U) {
    int b    = (blockIdx.x * blockDim.x + threadIdx.x) >> 6;
    int lane = threadIdx.x & 63;
    if (b >= B) return;
    int half = lane >> 5, sub = lane & 31;
    int row = half ? (item_ids[b] + U) : user_ids[b];
    size_t idx = (size_t)row * 32 + sub;
    unsigned u1 = l1[idx], u2 = l2[idx], u3 = l3[idx];
    float sx = bf_lo(u1) + bf_lo(u2) + bf_lo(u3);
    float sy = bf_hi(u1) + bf_hi(u2) + bf_hi(u3);
    float ox = __shfl_xor(sx, 32, 64);
    float oy = __shfl_xor(sy, 32, 64);
    float p = sx * ox + sy * oy;   // lanes 0-31: user*item partial dot
#pragma unroll
    for (int off = 16; off > 0; off >>= 1) p += __shfl_down(p, off, 64);
    if (lane == 0) {
        float du = (float)deg[user_ids[b]];
        float di = (float)deg[item_ids[b] + U];
        out[b] = p * sqrtf(du) * sqrtf(di) * (1.0f / (NUM_LAYERS * NUM_LAYERS));
    }
}

// ---------------- launch ----------------

extern "C" void kernel_launch(void* const* d_in, const int* in_sizes, int n_in,
                              void* d_out, int out_size, void* d_ws, size_t ws_size,
                              hipStream_t stream) {
    const float* user_emb = (const float*)d_in[0];
    const float* item_emb = (const float*)d_in[1];
    // d_in[2] (vals) unused: reconstructed algebraically from degrees
    const int*   rows     = (const int*)d_in[3];
    const int*   cols     = (const int*)d_in[4];
    const int*   user_ids = (const int*)d_in[5];
    const int*   item_ids = (const int*)d_in[6];
    float*       out      = (float*)d_out;

    const int U = in_sizes[0] / EMBED_DIM;
    const int I = in_sizes[1] / EMBED_DIM;
    const int E2 = in_sizes[3] >> 1;    // base pairs: rows=[u;v'], cols=[v';u]
    const int B = in_sizes[5];
    const int N = U + I;
    const int NB = (N + RMASK) >> RSHIFT;   // 256-row buckets
    const int BSPLIT = U >> RSHIFT;         // buckets below: pure users

    // total bin entries = bucket_base(NB)
    const long long TOT = (long long)((NB < BSPLIT ? NB : BSPLIT)) * CAPU +
                          (long long)((NB > BSPLIT) ? (NB - BSPLIT) : 0) * CAPI;

    // workspace layout (~104MB)
    char* w = (char*)d_ws;
    unsigned* x2      = (unsigned*)w; w += (size_t)N * 32 * sizeof(unsigned);   // w0, later L3
    unsigned* L1      = (unsigned*)w; w += (size_t)N * 32 * sizeof(unsigned);
    unsigned* L2      = (unsigned*)w; w += (size_t)N * 32 * sizeof(unsigned);
    int*      bin     = (int*)w;      w += (size_t)TOT * sizeof(int);
    int*      col_idx = (int*)w;      w += (size_t)TOT * sizeof(int);
    int*      row_ptr = (int*)w;      w += (size_t)N * sizeof(int);
    int*      deg     = (int*)w;      w += (size_t)N * sizeof(int);
    int*      gcur    = (int*)w;      w += (size_t)NB * sizeof(int);

    const int T = 256;
    const int GP = (E2 + TP - 1) / TP;

    // CSR build: split-capacity buckets, LDS-staged counting sort
    init_gcur_kernel<<<(NB + T - 1) / T, T, 0, stream>>>(gcur, NB, BSPLIT);
    split_kernel<<<GP, T, 0, stream>>>(rows, cols, gcur, bin, E2, NB);
    csr_kernel<<<NB, T, 0, stream>>>(bin, gcur, row_ptr, deg, col_idx, N, BSPLIT);

    // w0 = bf16pack(D^{-1/2} * concat(embeddings))
    w0_kernel<<<(N * 32 + T - 1) / T, T, 0, stream>>>((const float2*)user_emb,
                                                      (const float2*)item_emb,
                                                      deg, x2, U, N);

    // 3 propagation layers (neighbor mean); layer 3 reuses x2 as output
    const int GS = (N * 8 + T - 1) / T;   // one octet (8 threads) per row
    spmm_kernel<<<GS, T, 0, stream>>>(row_ptr, deg, col_idx,
                                      (const uint4*)x2, (uint4*)L1, N);
    spmm_kernel<<<GS, T, 0, stream>>>(row_ptr, deg, col_idx,
                                      (const uint4*)L1, (uint4*)L2, N);
    spmm_kernel<<<GS, T, 0, stream>>>(row_ptr, deg, col_idx,
                                      (const uint4*)L2, (uint4*)x2, N);

    readout_kernel<<<(B * 64 + T - 1) / T, T, 0, stream>>>(L1, L2, x2, deg,
                                                           user_ids, item_ids, out, B, U);
}

// Round 13
// 385.718 us; speedup vs baseline: 3.0989x; 1.0425x over previous
//
#include <hip/hip_runtime.h>

// XSimGCL / LightGCN propagation on MI355X.
// w = D^{-1/2} x  =>  each layer is an unweighted neighbor MEAN; no edge values.
// State = packed bf16 pairs, 128B rows.
// spmm: octet-per-row (r12 win: no shfl reduction), unroll-4 (r13: 4 gathers
// in flight — r12 showed VALU 28% / HBM 39% => latency-bound).
// Build: split-capacity buckets (r10: bucket load BIMODAL, CAPU 8192 /
// CAPI 12288), no global hist/scan; wave-shuffle scans (r13: barrier diet);
// w0 fused into csr (r13). r4: every global write is a contiguous run staged
// through LDS (scattered 4B stores pay ~64B HBM writeback each).

#define EMBED_DIM 64
#define NUM_LAYERS 3
#define RSHIFT 8            // 256 rows per bucket
#define RMASK 255
#define NBMAX 640           // supports N <= 163840
#define CAPU 8192           // user-bucket capacity (mean 5120)
#define CAPI 12288          // item-bucket capacity (mean 10240)
#define TP 6144             // base pairs per tile -> 2*TP staged entries
#define OUT_CAP 15360       // csr out-staging capacity (>= CAPI)

__device__ __forceinline__ int bucket_base(int b, int BSPLIT) {
    int lo = (b < BSPLIT) ? b : BSPLIT;
    int hi = (b > BSPLIT) ? (b - BSPLIT) : 0;
    return lo * CAPU + hi * CAPI;
}

// ---------------- bf16 pair helpers ----------------

__device__ __forceinline__ unsigned bf16pair(float a, float b) {
    unsigned ia = __float_as_uint(a);
    unsigned ib = __float_as_uint(b);
    ia = (ia + 0x7fffu + ((ia >> 16) & 1u)) >> 16;          // RNE, low half
    ib = (ib + 0x7fffu + ((ib >> 16) & 1u)) & 0xffff0000u;  // RNE, high half
    return ia | ib;
}
__device__ __forceinline__ float bf_lo(unsigned u) { return __uint_as_float(u << 16); }
__device__ __forceinline__ float bf_hi(unsigned u) { return __uint_as_float(u & 0xffff0000u); }

// ---------------- init: gcur[b] = bucket_base(b) ----------------

__global__ void init_gcur_kernel(int* __restrict__ gcur, int NB, int BSPLIT) {
    int b = blockIdx.x * blockDim.x + threadIdx.x;
    if (b < NB) gcur[b] = bucket_base(b, BSPLIT);
}

// ---------------- split: pairs -> 2 entries -> LDS bucket-grouped -> run copies ----------------

__global__ __launch_bounds__(256) void split_kernel(const int* __restrict__ uu,
                                                    const int* __restrict__ vv,
                                                    int* __restrict__ gcur,
                                                    int* __restrict__ bin, int E2, int NB) {
    __shared__ int h[NBMAX], exl[NBMAX], curb[NBMAX], gb[NBMAX];
    __shared__ int wp[4];
    __shared__ int stage[2 * TP];
    int tid = threadIdx.x;
    int lane = tid & 63, wid = tid >> 6;
    for (int i = tid; i < NB; i += 256) h[i] = 0;
    __syncthreads();
    int e0 = blockIdx.x * TP, e1 = min(e0 + TP, E2);
    // hist pass (int4-vectorized; e0 is 16B aligned)
    int j = e0 + tid * 4;
    for (; j + 3 < e1; j += 1024) {
        int4 u4 = *(const int4*)(uu + j);
        int4 v4 = *(const int4*)(vv + j);
        atomicAdd(&h[u4.x >> RSHIFT], 1); atomicAdd(&h[v4.x >> RSHIFT], 1);
        atomicAdd(&h[u4.y >> RSHIFT], 1); atomicAdd(&h[v4.y >> RSHIFT], 1);
        atomicAdd(&h[u4.z >> RSHIFT], 1); atomicAdd(&h[v4.z >> RSHIFT], 1);
        atomicAdd(&h[u4.w >> RSHIFT], 1); atomicAdd(&h[v4.w >> RSHIFT], 1);
    }
    for (; j < e1; ++j) {  // tail (last block only)
        atomicAdd(&h[uu[j] >> RSHIFT], 1);
        atomicAdd(&h[vv[j] >> RSHIFT], 1);
    }
    __syncthreads();
    // exclusive scan of h[0..NB) -> exl: 3 elems/thread + wave-shuffle scan
    {
        int b3 = tid * 3;
        int v0 = (b3     < NB) ? h[b3]     : 0;
        int v1 = (b3 + 1 < NB) ? h[b3 + 1] : 0;
        int v2 = (b3 + 2 < NB) ? h[b3 + 2] : 0;
        int tsum = v0 + v1 + v2;
        int x = tsum;
        for (int off = 1; off < 64; off <<= 1) {
            int y = __shfl_up(x, off, 64);
            if (lane >= off) x += y;
        }
        if (lane == 63) wp[wid] = x;
        __syncthreads();
        int wadd = 0;
        for (int k = 0; k < wid; ++k) wadd += wp[k];
        int tpre = wadd + x - tsum;
        if (b3     < NB) exl[b3]     = tpre;
        if (b3 + 1 < NB) exl[b3 + 1] = tpre + v0;
        if (b3 + 2 < NB) exl[b3 + 2] = tpre + v0 + v1;
        __syncthreads();
    }
    for (int b = tid; b < NB; b += 256) {
        curb[b] = exl[b];
        gb[b]   = h[b] ? atomicAdd(&gcur[b], h[b]) : 0;
    }
    __syncthreads();
    // scatter pass (int4-vectorized)
    j = e0 + tid * 4;
    for (; j + 3 < e1; j += 1024) {
        int4 u4 = *(const int4*)(uu + j);
        int4 v4 = *(const int4*)(vv + j);
        int p;
        p = atomicAdd(&curb[u4.x >> RSHIFT], 1); stage[p] = (v4.x << RSHIFT) | (u4.x & RMASK);
        p = atomicAdd(&curb[v4.x >> RSHIFT], 1); stage[p] = (u4.x << RSHIFT) | (v4.x & RMASK);
        p = atomicAdd(&curb[u4.y >> RSHIFT], 1); stage[p] = (v4.y << RSHIFT) | (u4.y & RMASK);
        p = atomicAdd(&curb[v4.y >> RSHIFT], 1); stage[p] = (u4.y << RSHIFT) | (v4.y & RMASK);
        p = atomicAdd(&curb[u4.z >> RSHIFT], 1); stage[p] = (v4.z << RSHIFT) | (u4.z & RMASK);
        p = atomicAdd(&curb[v4.z >> RSHIFT], 1); stage[p] = (u4.z << RSHIFT) | (v4.z & RMASK);
        p = atomicAdd(&curb[u4.w >> RSHIFT], 1); stage[p] = (v4.w << RSHIFT) | (u4.w & RMASK);
        p = atomicAdd(&curb[v4.w >> RSHIFT], 1); stage[p] = (u4.w << RSHIFT) | (v4.w & RMASK);
    }
    for (; j < e1; ++j) {
        int u = uu[j], v = vv[j];
        int p1 = atomicAdd(&curb[u >> RSHIFT], 1);
        stage[p1] = (v << RSHIFT) | (u & RMASK);
        int p2 = atomicAdd(&curb[v >> RSHIFT], 1);
        stage[p2] = (u << RSHIFT) | (v & RMASK);
    }
    __syncthreads();
    // copy runs out contiguously (one wave per bucket)
    for (int b = wid; b < NB; b += 4) {
        int cnt_b = h[b];
        int st = exl[b], g = gb[b];
        for (int k = lane; k < cnt_b; k += 64) bin[g + k] = stage[st + k];
    }
}

// ---------------- csr: per-bucket LDS counting sort + fused w0 ----------------

__global__ __launch_bounds__(256) void csr_kernel(const int* __restrict__ bin,
                                                  const int* __restrict__ gcur,
                                                  int* __restrict__ row_ptr,
                                                  int* __restrict__ deg,
                                                  int* __restrict__ col_idx,
                                                  const float2* __restrict__ ue,
                                                  const float2* __restrict__ ie,
                                                  unsigned* __restrict__ w0x,
                                                  int N, int U, int BSPLIT) {
    __shared__ int h2[256], cur2[256];
    __shared__ float rs2[256];
    __shared__ int wp[4];
    __shared__ __align__(16) int outst[OUT_CAP];
    int b   = blockIdx.x;
    int tid = threadIdx.x;
    int lane = tid & 63, wid = tid >> 6;
    int s = bucket_base(b, BSPLIT);
    int e = gcur[b];          // == s + bucket count (after split)
    int cnt = e - s;
    h2[tid] = 0;
    __syncthreads();
    // hist pass (int4; s is 16B aligned)
    int cnt4 = cnt >> 2;
    const int4* bin4 = (const int4*)(bin + s);
    for (int j = tid; j < cnt4; j += 256) {
        int4 v = bin4[j];
        atomicAdd(&h2[v.x & RMASK], 1);
        atomicAdd(&h2[v.y & RMASK], 1);
        atomicAdd(&h2[v.z & RMASK], 1);
        atomicAdd(&h2[v.w & RMASK], 1);
    }
    for (int j = (cnt4 << 2) + tid; j < cnt; j += 256) atomicAdd(&h2[bin[s + j] & RMASK], 1);
    __syncthreads();
    int myh = h2[tid];
    rs2[tid] = (myh > 0) ? rsqrtf((float)myh) : 0.0f;
    // exclusive scan of h2 via wave shuffles
    {
        int x = myh;
        for (int off = 1; off < 64; off <<= 1) {
            int y = __shfl_up(x, off, 64);
            if (lane >= off) x += y;
        }
        if (lane == 63) wp[wid] = x;
        __syncthreads();
        int wadd = 0;
        for (int k = 0; k < wid; ++k) wadd += wp[k];
        cur2[tid] = wadd + x - myh;   // exclusive
    }
    int gr = (b << RSHIFT) + tid;
    if (gr < N) {
        row_ptr[gr] = s + cur2[tid];
        deg[gr]     = myh;
    }
    __syncthreads();
    // placement pass
    if (cnt <= OUT_CAP) {
        for (int j = tid; j < cnt4; j += 256) {
            int4 v = bin4[j];
            int p;
            p = atomicAdd(&cur2[v.x & RMASK], 1); outst[p] = v.x >> RSHIFT;
            p = atomicAdd(&cur2[v.y & RMASK], 1); outst[p] = v.y >> RSHIFT;
            p = atomicAdd(&cur2[v.z & RMASK], 1); outst[p] = v.z >> RSHIFT;
            p = atomicAdd(&cur2[v.w & RMASK], 1); outst[p] = v.w >> RSHIFT;
        }
        for (int j = (cnt4 << 2) + tid; j < cnt; j += 256) {
            int v = bin[s + j];
            int p = atomicAdd(&cur2[v & RMASK], 1);
            outst[p] = v >> RSHIFT;
        }
        __syncthreads();
        int4* dst4 = (int4*)(col_idx + s);
        for (int j = tid; j < cnt4; j += 256) dst4[j] = ((const int4*)outst)[j];
        for (int j = (cnt4 << 2) + tid; j < cnt; j += 256) col_idx[s + j] = outst[j];
    } else {  // safety fallback
        for (int j = tid; j < cnt; j += 256) {
            int v = bin[s + j];
            int p = atomicAdd(&cur2[v & RMASK], 1);
            col_idx[s + p] = v >> RSHIFT;
        }
    }
    // fused w0: pack bf16(D^{-1/2} * emb) for this bucket's 256 rows
    for (int idx = tid; idx < 256 * 32; idx += 256) {
        int rl = idx >> 5, sub = idx & 31;
        int n = (b << RSHIFT) + rl;
        if (n < N) {
            float2 v = (n < U) ? ue[(size_t)n * 32 + sub] : ie[(size_t)(n - U) * 32 + sub];
            float rs = rs2[rl];
            w0x[(size_t)n * 32 + sub] = bf16pair(v.x * rs, v.y * rs);
        }
    }
}

// ---------------- SpMM: neighbor mean, octet-per-row, unroll-4 ----------------

__global__ __launch_bounds__(256) void spmm_kernel(const int* __restrict__ row_ptr,
                                                   const int* __restrict__ deg,
                                                   const int* __restrict__ col_idx,
                                                   const uint4* __restrict__ x4,
                                                   uint4* __restrict__ y4, int N) {
    int gw   = (blockIdx.x * blockDim.x + threadIdx.x) >> 6;
    int lane = threadIdx.x & 63;
    int oct  = lane >> 3, sub = lane & 7;
    int r = gw * 8 + oct;
    if (r >= N) return;
    int s = row_ptr[r];
    int d = deg[r];
    float2 a0 = {0, 0}, a1 = {0, 0}, a2 = {0, 0}, a3 = {0, 0};
    int k = 0;
    for (; k + 3 < d; k += 4) {
        int c0 = col_idx[s + k];
        int c1 = col_idx[s + k + 1];
        int c2 = col_idx[s + k + 2];
        int c3 = col_idx[s + k + 3];
        uint4 u0 = x4[(size_t)c0 * 8 + sub];
        uint4 u1 = x4[(size_t)c1 * 8 + sub];
        uint4 u2 = x4[(size_t)c2 * 8 + sub];
        uint4 u3 = x4[(size_t)c3 * 8 + sub];
        a0.x += bf_lo(u0.x); a0.y += bf_hi(u0.x);
        a1.x += bf_lo(u0.y); a1.y += bf_hi(u0.y);
        a2.x += bf_lo(u0.z); a2.y += bf_hi(u0.z);
        a3.x += bf_lo(u0.w); a3.y += bf_hi(u0.w);
        a0.x += bf_lo(u1.x); a0.y += bf_hi(u1.x);
        a1.x += bf_lo(u1.y); a1.y += bf_hi(u1.y);
        a2.x += bf_lo(u1.z); a2.y += bf_hi(u1.z);
        a3.x += bf_lo(u1.w); a3.y += bf_hi(u1.w);
        a0.x += bf_lo(u2.x); a0.y += bf_hi(u2.x);
        a1.x += bf_lo(u2.y); a1.y += bf_hi(u2.y);
        a2.x += bf_lo(u2.z); a2.y += bf_hi(u2.z);
        a3.x += bf_lo(u2.w); a3.y += bf_hi(u2.w);
        a0.x += bf_lo(u3.x); a0.y += bf_hi(u3.x);
        a1.x += bf_lo(u3.y); a1.y += bf_hi(u3.y);
        a2.x += bf_lo(u3.z); a2.y += bf_hi(u3.z);
        a3.x += bf_lo(u3.w); a3.y += bf_hi(u3.w);
    }
    for (; k < d; ++k) {
        int c0 = col_idx[s + k];
        uint4 u0 = x4[(size_t)c0 * 8 + sub];
        a0.x += bf_lo(u0.x); a0.y += bf_hi(u0.x);
        a1.x += bf_lo(u0.y); a1.y += bf_hi(u0.y);
        a2.x += bf_lo(u0.z); a2.y += bf_hi(u0.z);
        a3.x += bf_lo(u0.w); a3.y += bf_hi(u0.w);
    }
    float inv = (d > 0) ? (1.0f / (float)d) : 0.0f;
    uint4 o;
    o.x = bf16pair(a0.x * inv, a0.y * inv);
    o.y = bf16pair(a1.x * inv, a1.y * inv);
    o.z = bf16pair(a2.x * inv, a2.y * inv);
    o.w = bf16pair(a3.x * inv, a3.y * inv);
    y4[(size_t)r * 8 + sub] = o;
}

// ---------------- fused readout ----------------

__global__ __launch_bounds__(256) void readout_kernel(const unsigned* __restrict__ l1,
                                                      const unsigned* __restrict__ l2,
                                                      const unsigned* __restrict__ l3,
                                                      const int* __restrict__ deg,
                                                      const int* __restrict__ user_ids,
                                                      const int* __restrict__ item_ids,
                                                      float* __restrict__ out, int B, int U) {
    int b    = (blockIdx.x * blockDim.x + threadIdx.x) >> 6;
    int lane = threadIdx.x & 63;
    if (b >= B) return;
    int half = lane >> 5, sub = lane & 31;
    int row = half ? (item_ids[b] + U) : user_ids[b];
    size_t idx = (size_t)row * 32 + sub;
    unsigned u1 = l1[idx], u2 = l2[idx], u3 = l3[idx];
    float sx = bf_lo(u1) + bf_lo(u2) + bf_lo(u3);
    float sy = bf_hi(u1) + bf_hi(u2) + bf_hi(u3);
    float ox = __shfl_xor(sx, 32, 64);
    float oy = __shfl_xor(sy, 32, 64);
    float p = sx * ox + sy * oy;   // lanes 0-31: user*item partial dot
#pragma unroll
    for (int off = 16; off > 0; off >>= 1) p += __shfl_down(p, off, 64);
    if (lane == 0) {
        float du = (float)deg[user_ids[b]];
        float di = (float)deg[item_ids[b] + U];
        out[b] = p * sqrtf(du) * sqrtf(di) * (1.0f / (NUM_LAYERS * NUM_LAYERS));
    }
}

// ---------------- launch ----------------

extern "C" void kernel_launch(void* const* d_in, const int* in_sizes, int n_in,
                              void* d_out, int out_size, void* d_ws, size_t ws_size,
                              hipStream_t stream) {
    const float* user_emb = (const float*)d_in[0];
    const float* item_emb = (const float*)d_in[1];
    // d_in[2] (vals) unused: reconstructed algebraically from degrees
    const int*   rows     = (const int*)d_in[3];
    const int*   cols     = (const int*)d_in[4];
    const int*   user_ids = (const int*)d_in[5];
    const int*   item_ids = (const int*)d_in[6];
    float*       out      = (float*)d_out;

    const int U = in_sizes[0] / EMBED_DIM;
    const int I = in_sizes[1] / EMBED_DIM;
    const int E2 = in_sizes[3] >> 1;    // base pairs: rows=[u;v'], cols=[v';u]
    const int B = in_sizes[5];
    const int N = U + I;
    const int NB = (N + RMASK) >> RSHIFT;   // 256-row buckets
    const int BSPLIT = U >> RSHIFT;         // buckets below: pure users

    // total bin entries = bucket_base(NB)
    const long long TOT = (long long)((NB < BSPLIT ? NB : BSPLIT)) * CAPU +
                          (long long)((NB > BSPLIT) ? (NB - BSPLIT) : 0) * CAPI;

    // workspace layout (~104MB)
    char* w = (char*)d_ws;
    unsigned* x2      = (unsigned*)w; w += (size_t)N * 32 * sizeof(unsigned);   // w0, later L3
    unsigned* L1      = (unsigned*)w; w += (size_t)N * 32 * sizeof(unsigned);
    unsigned* L2      = (unsigned*)w; w += (size_t)N * 32 * sizeof(unsigned);
    int*      bin     = (int*)w;      w += (size_t)TOT * sizeof(int);
    int*      col_idx = (int*)w;      w += (size_t)TOT * sizeof(int);
    int*      row_ptr = (int*)w;      w += (size_t)N * sizeof(int);
    int*      deg     = (int*)w;      w += (size_t)N * sizeof(int);
    int*      gcur    = (int*)w;      w += (size_t)NB * sizeof(int);

    const int T = 256;
    const int GP = (E2 + TP - 1) / TP;

    // CSR build: split-capacity buckets, LDS-staged counting sort, fused w0
    init_gcur_kernel<<<(NB + T - 1) / T, T, 0, stream>>>(gcur, NB, BSPLIT);
    split_kernel<<<GP, T, 0, stream>>>(rows, cols, gcur, bin, E2, NB);
    csr_kernel<<<NB, T, 0, stream>>>(bin, gcur, row_ptr, deg, col_idx,
                                     (const float2*)user_emb, (const float2*)item_emb,
                                     x2, N, U, BSPLIT);

    // 3 propagation layers (neighbor mean); layer 3 reuses x2 as output
    const int GS = (N * 8 + T - 1) / T;   // one octet (8 threads) per row
    spmm_kernel<<<GS, T, 0, stream>>>(row_ptr, deg, col_idx,
                                      (const uint4*)x2, (uint4*)L1, N);
    spmm_kernel<<<GS, T, 0, stream>>>(row_ptr, deg, col_idx,
                                      (const uint4*)L1, (uint4*)L2, N);
    spmm_kernel<<<GS, T, 0, stream>>>(row_ptr, deg, col_idx,
                                      (const uint4*)L2, (uint4*)x2, N);

    readout_kernel<<<(B * 64 + T - 1) / T, T, 0, stream>>>(L1, L2, x2, deg,
                                                           user_ids, item_ids, out, B, U);
}